// Round 5
// baseline (913.819 us; speedup 1.0000x reference)
//
#include <hip/hip_runtime.h>

// WindowAttention for MI355X (gfx950) — round 5: split QKV-GEMM / attention kernels.
// B_=8192 windows, N=49 tokens, C=192, H=6 heads, dh=32, NW=64 masks.

#define NTOK 49
#define CCH 192

typedef __bf16 bf16_t;
typedef bf16_t bf16x8 __attribute__((ext_vector_type(8)));
typedef bf16_t bf16x4 __attribute__((ext_vector_type(4)));
typedef bf16_t bf16x2 __attribute__((ext_vector_type(2)));
typedef float f32x4 __attribute__((ext_vector_type(4)));

// ws byte offsets
#define WS_WQT   0         // 192*192 bf16, pre-scaled by dh^-0.5 * log2e
#define WS_WKVT  73728     // 384*192 bf16
#define WS_WPT   221184    // 192*192 bf16
#define WS_BQS   294912    // 192 f32 pre-scaled q-bias
#define WS_TBL   295680    // bias/mask tables (mode-dependent, log2e-scaled)
#define WS_QKV   5112576   // after mode-0 table: per-window {Q[49][192],K[49][192],V[49][192]} bf16
#define QKV_ELEMS_PER_WIN 28224   // 3*49*192
#define QKV_BYTES_PER_WIN 56448

#define SWZ(row, off) ((off) ^ (((row) & 7) << 4))

__device__ __forceinline__ unsigned pk2(float a, float b) {
    bf16x2 w = { (bf16_t)a, (bf16_t)b };
    return __builtin_bit_cast(unsigned, w);
}

__global__ void prep_kernel(const float* __restrict__ Wq, const float* __restrict__ bq,
                            const float* __restrict__ Wkv, const float* __restrict__ Wproj,
                            const float* __restrict__ btab, const int* __restrict__ rel,
                            const float* __restrict__ mask,
                            bf16_t* __restrict__ wqt, bf16_t* __restrict__ wkvt,
                            bf16_t* __restrict__ wpt, float* __restrict__ bqs,
                            float* __restrict__ tbl, int mode) {
    const float SC  = 0.2550718212080052f;   // dh^-0.5 * log2e
    const float L2E = 1.4426950408889634f;
    long i = (long)blockIdx.x * 256 + threadIdx.x;
    if (i < 36864) { int n = i / 192, k = i % 192; wqt[i] = (bf16_t)(Wq[k * 192 + n] * SC); return; }
    i -= 36864;
    if (i < 73728) { int n = i / 192, k = i % 192; wkvt[i] = (bf16_t)Wkv[k * 384 + n]; return; }
    i -= 73728;
    if (i < 36864) { int n = i / 192, k = i % 192; wpt[i] = (bf16_t)Wproj[k * 192 + n]; return; }
    i -= 36864;
    if (i < 192) { bqs[i] = bq[i] * SC; return; }
    i -= 192;
    if (mode == 0) {            // presummed [64][6][49][64], log2e-scaled, pad=-1e30
        if (i < 1204224) {
            int c = i & 63; long r = i >> 6; int q = r % 49; r /= 49; int h = r % 6; int w = r / 6;
            tbl[i] = (c < 49) ? (btab[rel[q * 49 + c] * 6 + h] + mask[(size_t)w * 2401 + q * 49 + c]) * L2E
                              : -1e30f;
        }
    } else if (mode == 1) {     // bias [6][49][64] (pad 0) + mask [64][49][64] (pad -1e30)
        if (i < 18816) { int c = i & 63; int r = i >> 6; int q = r % 49; int h = r / 49;
            tbl[i] = (c < 49) ? btab[rel[q * 49 + c] * 6 + h] * L2E : 0.f; return; }
        i -= 18816;
        if (i < 200704) { int c = i & 63; long r = i >> 6; int q = r % 49; int w = r / 49;
            tbl[18816 + i] = (c < 49) ? mask[(size_t)w * 2401 + q * 49 + c] * L2E : -1e30f; }
    } else {                    // raw gathered bias [6][49][49]
        if (i < 14406) { int h = i / 2401, rc = i % 2401; tbl[i] = btab[rel[rc] * 6 + h]; }
    }
}

// ---------------- Kernel 1: QKV projection (pure streaming, no LDS/barriers) ----------------
__global__ __launch_bounds__(512, 4) void qkv_kernel(
    const float* __restrict__ xq, const float* __restrict__ bkv,
    const bf16_t* __restrict__ wqt, const bf16_t* __restrict__ wkvt,
    const float* __restrict__ bqs, bf16_t* __restrict__ qkv, int base)
{
    const int tid = threadIdx.x;
    const int wid = tid >> 6;
    const int lane = tid & 63;
    const int l15 = lane & 15;
    const int lg = lane >> 4;
    const int b = base + blockIdx.x;
    const float* xp = xq + (size_t)b * (NTOK * CCH);
    bf16_t* og = qkv + (size_t)blockIdx.x * QKV_ELEMS_PER_WIN;

    const int mtp = wid & 1;             // token-tile pair {2*mtp, 2*mtp+1}
    const int ntq = wid >> 1;            // nt = ntq + 4k, k=0..8
    bf16x8 xf[2][6];
#pragma unroll
    for (int e = 0; e < 2; e++) {
        int tok = (mtp * 2 + e) * 16 + l15;
        const float* xrow = xp + (size_t)tok * 192;
        bool ok = (tok < NTOK);
#pragma unroll
        for (int ks = 0; ks < 6; ks++) {
            float4 a = { 0.f, 0.f, 0.f, 0.f }, c = { 0.f, 0.f, 0.f, 0.f };
            if (ok) {
                a = *(const float4*)(xrow + ks * 32 + lg * 8);
                c = *(const float4*)(xrow + ks * 32 + lg * 8 + 4);
            }
            bf16x8 f = { (bf16_t)a.x, (bf16_t)a.y, (bf16_t)a.z, (bf16_t)a.w,
                         (bf16_t)c.x, (bf16_t)c.y, (bf16_t)c.z, (bf16_t)c.w };
            xf[e][ks] = f;
        }
    }
    for (int k9 = 0; k9 < 9; k9++) {
        int nt = ntq + 4 * k9;                       // 0..35
        int kind = nt < 12 ? 0 : (nt < 24 ? 1 : 2);  // Q / K / V
        int ncol = (nt - (kind == 1 ? 12 : (kind == 2 ? 24 : 0))) * 16;
        int wofs = (kind == 2) ? 192 : 0;
        const bf16_t* wr = (kind == 0) ? (wqt + (size_t)(ncol + l15) * 192 + lg * 8)
                                       : (wkvt + (size_t)(wofs + ncol + l15) * 192 + lg * 8);
        float4 b4 = (kind == 0) ? *(const float4*)(bqs + ncol + lg * 4)
                                : *(const float4*)(bkv + wofs + ncol + lg * 4);
        bf16x8 bfr[6];
#pragma unroll
        for (int ks = 0; ks < 6; ks++) bfr[ks] = *(const bf16x8*)(wr + ks * 32);
        // swapped: D[outchan][token]; lane -> 4 consecutive outchans of token l15
        f32x4 acc0 = { b4.x, b4.y, b4.z, b4.w }, acc1 = acc0;
#pragma unroll
        for (int ks = 0; ks < 6; ks++) {
            acc0 = __builtin_amdgcn_mfma_f32_16x16x32_bf16(bfr[ks], xf[0][ks], acc0, 0, 0, 0);
            acc1 = __builtin_amdgcn_mfma_f32_16x16x32_bf16(bfr[ks], xf[1][ks], acc1, 0, 0, 0);
        }
        bf16_t* dstb = og + (kind == 0 ? 0 : (kind == 1 ? 9408 : 18816));
        int tr0 = mtp * 32 + l15;
        int tr1 = tr0 + 16;
        bf16x4 p0 = { (bf16_t)acc0[0], (bf16_t)acc0[1], (bf16_t)acc0[2], (bf16_t)acc0[3] };
        bf16x4 p1 = { (bf16_t)acc1[0], (bf16_t)acc1[1], (bf16_t)acc1[2], (bf16_t)acc1[3] };
        if (tr0 < NTOK) *(bf16x4*)(dstb + (size_t)tr0 * 192 + ncol + lg * 4) = p0;
        if (tr1 < NTOK) *(bf16x4*)(dstb + (size_t)tr1 * 192 + ncol + lg * 4) = p1;
    }
}

// ---------------- Kernel 2: attention + out-projection ----------------
__global__ __launch_bounds__(512, 4) void attn_kernel(
    const bf16_t* __restrict__ qkv, const float* __restrict__ mask,
    const bf16_t* __restrict__ wpt, const float* __restrict__ bproj,
    const float* __restrict__ tbl, float* __restrict__ out, int base, int mode)
{
    __shared__ __align__(16) unsigned char smem[73728];
    unsigned char* Ks = smem;            // [64][384B] K[token][chan]
    unsigned char* Vt = smem + 24576;    // [192][128B] V^T[chan][token]
    unsigned char* Os = smem + 49152;    // [64][384B] O[token][chan]

    const int tid = threadIdx.x;
    const int wid = tid >> 6;
    const int lane = tid & 63;
    const int l15 = lane & 15;
    const int lg = lane >> 4;
    const int t0 = blockIdx.x;
    const int bl = (t0 & ~63) | ((t0 & 7) << 3) | ((t0 >> 3) & 7);   // XCD-cluster swizzle
    const int b = base + bl;
    const int widx = b & 63;
    const float LOG2E = 1.4426950408889634f;

    const bf16_t* qg = qkv + (size_t)bl * QKV_ELEMS_PER_WIN;
    const bf16_t* kg = qg + 9408;
    const bf16_t* vg = qg + 18816;

    // stage K -> LDS (swizzled)
    for (int idx = tid; idx < 1176; idx += 512) {
        int row = idx / 24, c8 = (idx % 24) * 8;
        bf16x8 v = *(const bf16x8*)(kg + (size_t)row * 192 + c8);
        *(bf16x8*)(Ks + row * 384 + SWZ(row, c8 * 2)) = v;
    }
    if (tid < 512) {
        for (int idx = tid; idx < 720; idx += 512)
            *(unsigned long long*)(Ks + 49 * 384 + idx * 8) = 0ULL;
    }
    // stage V transposed -> Vt[chan][tok]
    for (int idx = tid; idx < 1176; idx += 512) {
        int row = idx / 24, c8 = (idx % 24) * 8;     // row = token
        bf16x8 v = *(const bf16x8*)(vg + (size_t)row * 192 + c8);
#pragma unroll
        for (int e = 0; e < 8; e++)
            *(bf16_t*)(Vt + (c8 + e) * 128 + SWZ(c8 + e, row * 2)) = v[e];
    }
    for (int idx = tid; idx < 2880; idx += 512) {    // zero Vt pad cols 49..63
        int ch = idx / 15, tc = 49 + idx % 15;
        *(bf16_t*)(Vt + ch * 128 + SWZ(ch, tc * 2)) = (bf16_t)0.f;
    }
    // prefetch Q fragments for this wave's 3 units (direct from global; no reuse)
    uint4 zz = { 0u, 0u, 0u, 0u };
    bf16x8 qf[3];
#pragma unroll
    for (int i3 = 0; i3 < 3; i3++) {
        int u = wid + 8 * i3, h = u >> 2, qtl = u & 3;
        int qrow = qtl * 16 + l15;
        qf[i3] = (qrow < NTOK) ? *(const bf16x8*)(qg + (size_t)qrow * 192 + h * 32 + lg * 8)
                               : __builtin_bit_cast(bf16x8, zz);
    }
    // prefetch unit-0 bias+mask table rows (mode 0)
    float4 tb0[4], tb1[4];
    auto tload = [&](int i3, float4* dst) {
        int u = wid + 8 * i3, h = u >> 2, qtl = u & 3;
        int q = qtl * 16 + l15;
        if (q < NTOK) {
            const float* tp = tbl + (((size_t)(widx * 6 + h) * 49 + q) << 6) + lg * 4;
#pragma unroll
            for (int f = 0; f < 4; f++) dst[f] = *(const float4*)(tp + f * 16);
        } else {
#pragma unroll
            for (int f = 0; f < 4; f++) dst[f] = make_float4(0.f, 0.f, 0.f, 0.f);
        }
    };
    if (mode == 0) tload(0, tb0);
    __syncthreads();

    // ---- attention: 24 (head,qtile) units, 3 per wave ----
#pragma unroll
    for (int i3 = 0; i3 < 3; i3++) {
        int u = wid + 8 * i3;
        int h = u >> 2, qtl = u & 3;
        bf16x8 qfr = qf[i3];
        if (mode == 0 && i3 < 2) tload(i3 + 1, (i3 & 1) ? tb0 : tb1);
        // QK^T (S^T orientation: col=q, row=ktok)
        f32x4 s[4];
#pragma unroll
        for (int f = 0; f < 4; f++) {
            int kr = f * 16 + l15;
            bf16x8 kfr = *(const bf16x8*)(Ks + kr * 384 + SWZ(kr, h * 64 + lg * 16));
            f32x4 z = { 0.f, 0.f, 0.f, 0.f };
            s[f] = __builtin_amdgcn_mfma_f32_16x16x32_bf16(kfr, qfr, z, 0, 0, 0);
        }
        int q = qtl * 16 + l15;
        bool qok = (q < NTOK);
        if (mode == 0) {
            const float4* tbc = (i3 & 1) ? tb1 : tb0;
#pragma unroll
            for (int f = 0; f < 4; f++) {
                if (qok) { s[f][0] += tbc[f].x; s[f][1] += tbc[f].y; s[f][2] += tbc[f].z; s[f][3] += tbc[f].w; }
                else {
#pragma unroll
                    for (int j = 0; j < 4; j++) { int k = f * 16 + lg * 4 + j; if (k >= NTOK) s[f][j] = -1e30f; }
                }
            }
            if (qok) { /* pad cols already -1e30 in table */ }
        } else if (mode == 1) {
#pragma unroll
            for (int f = 0; f < 4; f++) {
                if (qok) {
                    float4 b1 = *(const float4*)(tbl + (((size_t)(h * 49 + q)) << 6) + f * 16 + lg * 4);
                    float4 m1 = *(const float4*)(tbl + 18816 + (((size_t)(widx * 49 + q)) << 6) + f * 16 + lg * 4);
                    s[f][0] += b1.x + m1.x; s[f][1] += b1.y + m1.y;
                    s[f][2] += b1.z + m1.z; s[f][3] += b1.w + m1.w;
                } else {
#pragma unroll
                    for (int j = 0; j < 4; j++) { int k = f * 16 + lg * 4 + j; if (k >= NTOK) s[f][j] = -1e30f; }
                }
            }
        } else {
#pragma unroll
            for (int f = 0; f < 4; f++)
#pragma unroll
                for (int j = 0; j < 4; j++) {
                    int k = f * 16 + lg * 4 + j;
                    if (k >= NTOK) s[f][j] = -1e30f;
                    else if (qok)
                        s[f][j] += (tbl[h * 2401 + q * 49 + k] + mask[(size_t)widx * 2401 + q * 49 + k]) * LOG2E;
                }
        }
        // mode-0 pad-q rows: table zeros, pad cols not masked -> mask them
        if (mode == 0 && !qok) {
#pragma unroll
            for (int f = 0; f < 4; f++)
#pragma unroll
                for (int j = 0; j < 4; j++) { int k = f * 16 + lg * 4 + j; if (k >= NTOK) s[f][j] = -1e30f; }
        }
        // softmax over k (exp2 domain)
        float m = s[0][0];
#pragma unroll
        for (int f = 0; f < 4; f++)
#pragma unroll
            for (int j = 0; j < 4; j++) m = fmaxf(m, s[f][j]);
        m = fmaxf(m, __shfl_xor(m, 16));
        m = fmaxf(m, __shfl_xor(m, 32));
        float t = 0.f;
#pragma unroll
        for (int f = 0; f < 4; f++)
#pragma unroll
            for (int j = 0; j < 4; j++) { s[f][j] = __builtin_amdgcn_exp2f(s[f][j] - m); t += s[f][j]; }
        t += __shfl_xor(t, 16);
        t += __shfl_xor(t, 32);
        float inv = __builtin_amdgcn_rcpf(t);
        // pack P (unnormalized), reshuffle into PV B-operand layout
        unsigned Wp[8];
#pragma unroll
        for (int f = 0; f < 4; f++) {
            Wp[f * 2 + 0] = pk2(s[f][0], s[f][1]);
            Wp[f * 2 + 1] = pk2(s[f][2], s[f][3]);
        }
        bf16x8 pa[2];
#pragma unroll
        for (int ks2 = 0; ks2 < 2; ks2++) {
            unsigned pw[4];
#pragma unroll
            for (int p = 0; p < 4; p++) {
                int src = l15 + 16 * (((lg & 1) << 1) | (p >> 1));
                unsigned v0 = (unsigned)__shfl((int)Wp[(2 * ks2) * 2 + (p & 1)], src, 64);
                unsigned v1 = (unsigned)__shfl((int)Wp[(2 * ks2 + 1) * 2 + (p & 1)], src, 64);
                pw[p] = (lg & 2) ? v1 : v0;
            }
            uint4 pp = { pw[0], pw[1], pw[2], pw[3] };
            pa[ks2] = __builtin_bit_cast(bf16x8, pp);
        }
        // PV (swapped): D[chan][q]; normalize post-hoc
#pragma unroll
        for (int dt = 0; dt < 2; dt++) {
            f32x4 acc = { 0.f, 0.f, 0.f, 0.f };
#pragma unroll
            for (int ks2 = 0; ks2 < 2; ks2++) {
                int vr = h * 32 + dt * 16 + l15;
                bf16x8 vfr = *(const bf16x8*)(Vt + vr * 128 + SWZ(vr, ks2 * 64 + lg * 16));
                acc = __builtin_amdgcn_mfma_f32_16x16x32_bf16(vfr, pa[ks2], acc, 0, 0, 0);
            }
            int orow = qtl * 16 + l15;
            bf16x4 op4 = { (bf16_t)(acc[0] * inv), (bf16_t)(acc[1] * inv),
                           (bf16_t)(acc[2] * inv), (bf16_t)(acc[3] * inv) };
            *(bf16x4*)(Os + orow * 384 + SWZ(orow, h * 64 + dt * 32 + lg * 8)) = op4;
        }
    }
    __syncthreads();

    // ---- out projection (swapped), float4 global stores; 6 units/wave ----
    {
        float* op = out + (size_t)b * (NTOK * CCH);
        bf16x8 bfr[6];
        float4 b4 = { 0.f, 0.f, 0.f, 0.f };
        int prev_nt = -1;
        for (int i = 0; i < 6; i++) {
            int u = wid * 6 + i;
            int nt = u >> 2, mt = u & 3;
            if (nt != prev_nt) {
                prev_nt = nt;
                const bf16_t* wr = wpt + (size_t)(nt * 16 + l15) * 192 + lg * 8;
#pragma unroll
                for (int ks = 0; ks < 6; ks++) bfr[ks] = *(const bf16x8*)(wr + ks * 32);
                b4 = *(const float4*)(bproj + nt * 16 + lg * 4);
            }
            int orow = mt * 16 + l15;
            f32x4 acc = { b4.x, b4.y, b4.z, b4.w };
#pragma unroll
            for (int ks = 0; ks < 6; ks++) {
                bf16x8 of = *(const bf16x8*)(Os + orow * 384 + SWZ(orow, ks * 64 + lg * 16));
                acc = __builtin_amdgcn_mfma_f32_16x16x32_bf16(bfr[ks], of, acc, 0, 0, 0);
            }
            if (orow < NTOK) {
                float4 st = { acc[0], acc[1], acc[2], acc[3] };
                *(float4*)(op + orow * 192 + nt * 16 + lg * 4) = st;
            }
        }
    }
}

// ---------------- Monolithic fallback (round-4 kernel, proven) ----------------
__global__ __launch_bounds__(512, 4) void wattn_mono(
    const float* __restrict__ xq, const float* __restrict__ mask,
    const float* __restrict__ bkv, const float* __restrict__ bproj,
    const bf16_t* __restrict__ wqt, const bf16_t* __restrict__ wkvt, const bf16_t* __restrict__ wpt,
    const float* __restrict__ bqs, const float* __restrict__ tbl,
    float* __restrict__ out, int mode)
{
    __shared__ __align__(16) unsigned char smem[73728];
    unsigned char* QsO = smem;
    unsigned char* Ks  = smem + 24576;
    unsigned char* Vt  = smem + 49152;

    const int tid = threadIdx.x;
    const int wid = tid >> 6;
    const int lane = tid & 63;
    const int l15 = lane & 15;
    const int lg = lane >> 4;
    const int t0 = blockIdx.x;
    const int b = (t0 & 0x1FC0) | ((t0 & 7) << 3) | ((t0 >> 3) & 7);
    const float* xp = xq + (size_t)b * (NTOK * CCH);
    const float LOG2E = 1.4426950408889634f;

    const int mtp = wid & 1;
    const int ntq = wid >> 1;
    bf16x8 xf[2][6];
#pragma unroll
    for (int e = 0; e < 2; e++) {
        int tok = (mtp * 2 + e) * 16 + l15;
        const float* xrow = xp + (size_t)tok * 192;
        bool ok = (tok < NTOK);
#pragma unroll
        for (int ks = 0; ks < 6; ks++) {
            float4 a = { 0.f, 0.f, 0.f, 0.f }, c = { 0.f, 0.f, 0.f, 0.f };
            if (ok) {
                a = *(const float4*)(xrow + ks * 32 + lg * 8);
                c = *(const float4*)(xrow + ks * 32 + lg * 8 + 4);
            }
            bf16x8 f = { (bf16_t)a.x, (bf16_t)a.y, (bf16_t)a.z, (bf16_t)a.w,
                         (bf16_t)c.x, (bf16_t)c.y, (bf16_t)c.z, (bf16_t)c.w };
            xf[e][ks] = f;
        }
    }
    for (int k9 = 0; k9 < 9; k9++) {
        int nt = ntq + 4 * k9;
        int kind = nt < 12 ? 0 : (nt < 24 ? 1 : 2);
        int ncol = (nt - (kind == 1 ? 12 : (kind == 2 ? 24 : 0))) * 16;
        const bf16_t* wr;
        if (kind == 0)      wr = wqt  + (size_t)(ncol + l15) * 192 + lg * 8;
        else if (kind == 1) wr = wkvt + (size_t)(ncol + l15) * 192 + lg * 8;
        else                wr = wkvt + (size_t)(192 + ncol + l15) * 192 + lg * 8;
        bf16x8 bfr[6];
#pragma unroll
        for (int ks = 0; ks < 6; ks++) bfr[ks] = *(const bf16x8*)(wr + ks * 32);
        if (kind < 2) {
            float4 b4 = (kind == 0) ? *(const float4*)(bqs + ncol + lg * 4)
                                    : *(const float4*)(bkv + ncol + lg * 4);
            f32x4 acc0 = { b4.x, b4.y, b4.z, b4.w }, acc1 = acc0;
#pragma unroll
            for (int ks = 0; ks < 6; ks++) {
                acc0 = __builtin_amdgcn_mfma_f32_16x16x32_bf16(bfr[ks], xf[0][ks], acc0, 0, 0, 0);
                acc1 = __builtin_amdgcn_mfma_f32_16x16x32_bf16(bfr[ks], xf[1][ks], acc1, 0, 0, 0);
            }
            unsigned char* dst = (kind == 0) ? QsO : Ks;
            int tr0 = (mtp * 2) * 16 + l15;
            int tr1 = tr0 + 16;
            bf16x4 p0 = { (bf16_t)acc0[0], (bf16_t)acc0[1], (bf16_t)acc0[2], (bf16_t)acc0[3] };
            bf16x4 p1 = { (bf16_t)acc1[0], (bf16_t)acc1[1], (bf16_t)acc1[2], (bf16_t)acc1[3] };
            *(bf16x4*)(dst + tr0 * 384 + SWZ(tr0, ncol * 2 + lg * 8)) = p0;
            *(bf16x4*)(dst + tr1 * 384 + SWZ(tr1, ncol * 2 + lg * 8)) = p1;
        } else {
            float bv = bkv[192 + ncol + l15];
            f32x4 acc0 = { bv, bv, bv, bv }, acc1 = acc0;
#pragma unroll
            for (int ks = 0; ks < 6; ks++) {
                acc0 = __builtin_amdgcn_mfma_f32_16x16x32_bf16(xf[0][ks], bfr[ks], acc0, 0, 0, 0);
                acc1 = __builtin_amdgcn_mfma_f32_16x16x32_bf16(xf[1][ks], bfr[ks], acc1, 0, 0, 0);
            }
            int vr = ncol + l15;
            bf16x4 v0 = { (bf16_t)acc0[0], (bf16_t)acc0[1], (bf16_t)acc0[2], (bf16_t)acc0[3] };
            bf16x4 v1 = { (bf16_t)acc1[0], (bf16_t)acc1[1], (bf16_t)acc1[2], (bf16_t)acc1[3] };
            *(bf16x4*)(Vt + vr * 128 + SWZ(vr, (mtp * 2) * 32 + lg * 8)) = v0;
            *(bf16x4*)(Vt + vr * 128 + SWZ(vr, (mtp * 2 + 1) * 32 + lg * 8)) = v1;
        }
    }
    __syncthreads();

    const int widx = b & 63;
    for (int i3 = 0; i3 < 3; i3++) {
        int u = wid + 8 * i3;
        int h = u >> 2, qtl = u & 3;
        int qrow = qtl * 16 + l15;
        bf16x8 qfr = *(const bf16x8*)(QsO + qrow * 384 + SWZ(qrow, h * 64 + lg * 16));
        f32x4 s[4];
#pragma unroll
        for (int f = 0; f < 4; f++) {
            int kr = f * 16 + l15;
            bf16x8 kfr = *(const bf16x8*)(Ks + kr * 384 + SWZ(kr, h * 64 + lg * 16));
            f32x4 z = { 0.f, 0.f, 0.f, 0.f };
            s[f] = __builtin_amdgcn_mfma_f32_16x16x32_bf16(kfr, qfr, z, 0, 0, 0);
        }
        int q = qtl * 16 + l15;
        bool qok = (q < NTOK);
        if (mode == 0) {
#pragma unroll
            for (int f = 0; f < 4; f++) {
                if (qok) {
                    float4 bm = *(const float4*)(tbl + (((size_t)(widx * 6 + h) * 49 + q) << 6) + f * 16 + lg * 4);
                    s[f][0] += bm.x; s[f][1] += bm.y; s[f][2] += bm.z; s[f][3] += bm.w;
                } else {
#pragma unroll
                    for (int j = 0; j < 4; j++) { int k = f * 16 + lg * 4 + j; if (k >= NTOK) s[f][j] = -1e30f; }
                }
            }
        } else if (mode == 1) {
#pragma unroll
            for (int f = 0; f < 4; f++) {
                if (qok) {
                    float4 b1 = *(const float4*)(tbl + (((size_t)(h * 49 + q)) << 6) + f * 16 + lg * 4);
                    float4 m1 = *(const float4*)(tbl + 18816 + (((size_t)(widx * 49 + q)) << 6) + f * 16 + lg * 4);
                    s[f][0] += b1.x + m1.x; s[f][1] += b1.y + m1.y;
                    s[f][2] += b1.z + m1.z; s[f][3] += b1.w + m1.w;
                } else {
#pragma unroll
                    for (int j = 0; j < 4; j++) { int k = f * 16 + lg * 4 + j; if (k >= NTOK) s[f][j] = -1e30f; }
                }
            }
        } else {
#pragma unroll
            for (int f = 0; f < 4; f++)
#pragma unroll
                for (int j = 0; j < 4; j++) {
                    int k = f * 16 + lg * 4 + j;
                    if (k >= NTOK) s[f][j] = -1e30f;
                    else if (qok)
                        s[f][j] += (tbl[h * 2401 + q * 49 + k] + mask[(size_t)widx * 2401 + q * 49 + k]) * LOG2E;
                }
        }
        float m = s[0][0];
#pragma unroll
        for (int f = 0; f < 4; f++)
#pragma unroll
            for (int j = 0; j < 4; j++) m = fmaxf(m, s[f][j]);
        m = fmaxf(m, __shfl_xor(m, 16));
        m = fmaxf(m, __shfl_xor(m, 32));
        float t = 0.f;
#pragma unroll
        for (int f = 0; f < 4; f++)
#pragma unroll
            for (int j = 0; j < 4; j++) { s[f][j] = __builtin_amdgcn_exp2f(s[f][j] - m); t += s[f][j]; }
        t += __shfl_xor(t, 16);
        t += __shfl_xor(t, 32);
        float inv = __builtin_amdgcn_rcpf(t);
        unsigned Wp[8];
#pragma unroll
        for (int f = 0; f < 4; f++) {
            Wp[f * 2 + 0] = pk2(s[f][0], s[f][1]);
            Wp[f * 2 + 1] = pk2(s[f][2], s[f][3]);
        }
        bf16x8 pa[2];
#pragma unroll
        for (int ks2 = 0; ks2 < 2; ks2++) {
            unsigned pw[4];
#pragma unroll
            for (int p = 0; p < 4; p++) {
                int src = l15 + 16 * (((lg & 1) << 1) | (p >> 1));
                unsigned v0 = (unsigned)__shfl((int)Wp[(2 * ks2) * 2 + (p & 1)], src, 64);
                unsigned v1 = (unsigned)__shfl((int)Wp[(2 * ks2 + 1) * 2 + (p & 1)], src, 64);
                pw[p] = (lg & 2) ? v1 : v0;
            }
            uint4 pp = { pw[0], pw[1], pw[2], pw[3] };
            pa[ks2] = __builtin_bit_cast(bf16x8, pp);
        }
#pragma unroll
        for (int dt = 0; dt < 2; dt++) {
            f32x4 acc = { 0.f, 0.f, 0.f, 0.f };
#pragma unroll
            for (int ks2 = 0; ks2 < 2; ks2++) {
                int vr = h * 32 + dt * 16 + l15;
                bf16x8 vfr = *(const bf16x8*)(Vt + vr * 128 + SWZ(vr, ks2 * 64 + lg * 16));
                acc = __builtin_amdgcn_mfma_f32_16x16x32_bf16(vfr, pa[ks2], acc, 0, 0, 0);
            }
            int orow = qtl * 16 + l15;
            bf16x4 op4 = { (bf16_t)(acc[0] * inv), (bf16_t)(acc[1] * inv),
                           (bf16_t)(acc[2] * inv), (bf16_t)(acc[3] * inv) };
            *(bf16x4*)(QsO + orow * 384 + SWZ(orow, h * 64 + dt * 32 + lg * 8)) = op4;
        }
    }
    __syncthreads();

    {
        float* op = out + (size_t)b * (NTOK * CCH);
        bf16x8 bfr[6];
        float4 b4 = { 0.f, 0.f, 0.f, 0.f };
        int prev_nt = -1;
        for (int i = 0; i < 6; i++) {
            int u = wid * 6 + i;
            int nt = u >> 2, mt = u & 3;
            if (nt != prev_nt) {
                prev_nt = nt;
                const bf16_t* wr = wpt + (size_t)(nt * 16 + l15) * 192 + lg * 8;
#pragma unroll
                for (int ks = 0; ks < 6; ks++) bfr[ks] = *(const bf16x8*)(wr + ks * 32);
                b4 = *(const float4*)(bproj + nt * 16 + lg * 4);
            }
            int orow = mt * 16 + l15;
            f32x4 acc = { b4.x, b4.y, b4.z, b4.w };
#pragma unroll
            for (int ks = 0; ks < 6; ks++) {
                bf16x8 of = *(const bf16x8*)(QsO + orow * 384 + SWZ(orow, ks * 64 + lg * 16));
                acc = __builtin_amdgcn_mfma_f32_16x16x32_bf16(bfr[ks], of, acc, 0, 0, 0);
            }
            if (orow < NTOK) {
                float4 st = { acc[0], acc[1], acc[2], acc[3] };
                *(float4*)(op + orow * 192 + nt * 16 + lg * 4) = st;
            }
        }
    }
}

extern "C" void kernel_launch(void* const* d_in, const int* in_sizes, int n_in,
                              void* d_out, int out_size, void* d_ws, size_t ws_size,
                              hipStream_t stream) {
    const float* xq    = (const float*)d_in[0];
    const float* mask  = (const float*)d_in[1];
    const float* Wq    = (const float*)d_in[2];
    const float* bq    = (const float*)d_in[3];
    const float* Wkv   = (const float*)d_in[4];
    const float* bkv   = (const float*)d_in[5];
    const float* Wproj = (const float*)d_in[6];
    const float* bproj = (const float*)d_in[7];
    const float* btab  = (const float*)d_in[8];
    const int*   rel   = (const int*)d_in[9];
    float* out = (float*)d_out;

    char* ws = (char*)d_ws;
    bf16_t* wqt  = (bf16_t*)(ws + WS_WQT);
    bf16_t* wkvt = (bf16_t*)(ws + WS_WKVT);
    bf16_t* wpt  = (bf16_t*)(ws + WS_WPT);
    float*  bqs  = (float*)(ws + WS_BQS);
    float*  tbl  = (float*)(ws + WS_TBL);

    size_t need0 = (size_t)WS_TBL + 1204224u * 4u;
    size_t need1 = (size_t)WS_TBL + 219520u * 4u;
    int mode = (ws_size >= need0) ? 0 : (ws_size >= need1 ? 1 : 2);

    long tblN = (mode == 0) ? 1204224L : (mode == 1 ? 219520L : 14406L);
    long prep_elems = 147648L + tblN;
    int prep_blocks = (int)((prep_elems + 255) / 256);
    prep_kernel<<<prep_blocks, 256, 0, stream>>>(Wq, bq, Wkv, Wproj, btab, rel, mask,
                                                 wqt, wkvt, wpt, bqs, tbl, mode);

    size_t avail = (ws_size > (size_t)WS_QKV) ? ws_size - (size_t)WS_QKV : 0;
    long w_c_l = (long)(avail / QKV_BYTES_PER_WIN) & ~63L;
    int w_c = (int)(w_c_l > 8192 ? 8192 : w_c_l);

    if (w_c >= 64 && mode == 0) {
        bf16_t* qkvb = (bf16_t*)(ws + WS_QKV);
        for (int base = 0; base < 8192; base += w_c) {
            int n = (8192 - base) < w_c ? (8192 - base) : w_c;
            qkv_kernel<<<n, 512, 0, stream>>>(xq, bkv, wqt, wkvt, bqs, qkvb, base);
            attn_kernel<<<n, 512, 0, stream>>>(qkvb, mask, wpt, bproj, tbl, out, base, mode);
        }
    } else {
        wattn_mono<<<8192, 512, 0, stream>>>(xq, mask, bkv, bproj, wqt, wkvt, wpt,
                                             bqs, tbl, out, mode);
    }
}

// Round 7
// 672.653 us; speedup vs baseline: 1.3585x; 1.3585x over previous
//
#include <hip/hip_runtime.h>

// WindowAttention for MI355X (gfx950) — round 7 (round 6 with index-math fixes).
// Kernel A (qkv2): weight-stationary QKV GEMM, X staged in LDS per window,
//   tiled coalesced outputs. Kernel B (attn2): attention + out-proj from tiled QKV.
// B_=8192 windows, N=49 tokens, C=192, H=6 heads, dh=32, NW=64 masks.

#define NTOK 49
#define CCH 192
#define WPB 8              // windows per block in kernel A

typedef __bf16 bf16_t;
typedef bf16_t bf16x8 __attribute__((ext_vector_type(8)));
typedef bf16_t bf16x4 __attribute__((ext_vector_type(4)));
typedef bf16_t bf16x2 __attribute__((ext_vector_type(2)));
typedef float f32x4 __attribute__((ext_vector_type(4)));

// ws byte offsets
#define WS_WQT   0         // 192*192 bf16, pre-scaled by dh^-0.5 * log2e
#define WS_WKVT  73728     // 384*192 bf16
#define WS_WPT   221184    // 192*192 bf16
#define WS_BQS   294912    // 192 f32 pre-scaled q-bias
#define WS_TBL   295680    // bias/mask tables (mode-dependent, log2e-scaled)
#define WS_QKV   5112576   // QKV buffers after mode-0 table
#define QT_WIN   9408      // elems per window of tiled Q (12*49*16); K same
#define VT_WIN   10752     // elems per window of tiled V (192*56)
#define QKV_BYTES_PER_WIN 59136   // (9408*2 + 10752) * 2B

#define SWZ(row, off) ((off) ^ (((row) & 7) << 4))

__device__ __forceinline__ unsigned pk2(float a, float b) {
    bf16x2 w = { (bf16_t)a, (bf16_t)b };
    return __builtin_bit_cast(unsigned, w);
}

__global__ void prep_kernel(const float* __restrict__ Wq, const float* __restrict__ bq,
                            const float* __restrict__ Wkv, const float* __restrict__ Wproj,
                            const float* __restrict__ btab, const int* __restrict__ rel,
                            const float* __restrict__ mask,
                            bf16_t* __restrict__ wqt, bf16_t* __restrict__ wkvt,
                            bf16_t* __restrict__ wpt, float* __restrict__ bqs,
                            float* __restrict__ tbl, int mode) {
    const float SC  = 0.2550718212080052f;   // dh^-0.5 * log2e
    const float L2E = 1.4426950408889634f;
    long i = (long)blockIdx.x * 256 + threadIdx.x;
    if (i < 36864) { int n = i / 192, k = i % 192; wqt[i] = (bf16_t)(Wq[k * 192 + n] * SC); return; }
    i -= 36864;
    if (i < 73728) { int n = i / 192, k = i % 192; wkvt[i] = (bf16_t)Wkv[k * 384 + n]; return; }
    i -= 73728;
    if (i < 36864) { int n = i / 192, k = i % 192; wpt[i] = (bf16_t)Wproj[k * 192 + n]; return; }
    i -= 36864;
    if (i < 192) { bqs[i] = bq[i] * SC; return; }
    i -= 192;
    if (mode == 0) {            // presummed [64][6][49][64], log2e-scaled, pad=-1e30
        if (i < 1204224) {
            int c = i & 63; long r = i >> 6; int q = r % 49; r /= 49; int h = r % 6; int w = r / 6;
            tbl[i] = (c < 49) ? (btab[rel[q * 49 + c] * 6 + h] + mask[(size_t)w * 2401 + q * 49 + c]) * L2E
                              : -1e30f;
        }
    } else if (mode == 1) {
        if (i < 18816) { int c = i & 63; int r = i >> 6; int q = r % 49; int h = r / 49;
            tbl[i] = (c < 49) ? btab[rel[q * 49 + c] * 6 + h] * L2E : 0.f; return; }
        i -= 18816;
        if (i < 200704) { int c = i & 63; long r = i >> 6; int q = r % 49; int w = r / 49;
            tbl[18816 + i] = (c < 49) ? mask[(size_t)w * 2401 + q * 49 + c] * L2E : -1e30f; }
    } else {
        if (i < 14406) { int h = i / 2401, rc = i % 2401; tbl[i] = btab[rel[rc] * 6 + h]; }
    }
}

// ---------------- Kernel A: weight-stationary QKV projection ----------------
// Pairs p=0..17 of 16-col output tiles: p<6 Q, p<12 K, else V.
// Wave w handles pairs {w, w+8}; pairs 16,17 rotate over waves by window.
__global__ __launch_bounds__(512) void qkv2_kernel(
    const float* __restrict__ xq, const float* __restrict__ bkv,
    const bf16_t* __restrict__ wqt, const bf16_t* __restrict__ wkvt,
    const float* __restrict__ bqs,
    bf16_t* __restrict__ qt, bf16_t* __restrict__ kt, bf16_t* __restrict__ vt,
    int base)
{
    __shared__ __align__(16) unsigned char Xs[24576];   // [64][384B] bf16, swizzled
    const int tid = threadIdx.x;
    const int wid = tid >> 6;
    const int lane = tid & 63;
    const int l15 = lane & 15;
    const int lg = lane >> 4;

    for (int i = 0; i < WPB; i++) {
        const int lw = blockIdx.x * WPB + i;
        const float* xp = xq + (size_t)(base + lw) * (NTOK * CCH);
        // stage X -> bf16 LDS (rows 49..63 zero)
        for (int idx = tid; idx < 2352; idx += 512) {
            int row = idx / 48, c4 = idx % 48;
            float4 v = *(const float4*)(xp + row * 192 + c4 * 4);
            bf16x4 pk = { (bf16_t)v.x, (bf16_t)v.y, (bf16_t)v.z, (bf16_t)v.w };
            *(bf16x4*)(Xs + row * 384 + SWZ(row, c4 * 8)) = pk;
        }
        for (int idx = tid; idx < 720; idx += 512)
            *(unsigned long long*)(Xs + 49 * 384 + idx * 8) = 0ULL;
        __syncthreads();

        const int ep = (lw & 3) << 1;   // wave ep does pair 16, wave ep+1 does pair 17
        for (int sp = 0; sp < 3; sp++) {
            int p;
            if (sp == 0) p = wid;
            else if (sp == 1) p = wid + 8;
            else if (wid == ep) p = 16;
            else if (wid == ep + 1) p = 17;
            else break;                  // wave-uniform; no barrier inside

            const int kind = (p < 6) ? 0 : (p < 12 ? 1 : 2);
            const int rp = (kind == 0) ? 0 : (kind == 1 ? 6 : 12);   // pair base
            const int c0 = (p - rp) * 32;          // relative col base of tile0
            const int c1 = c0 + 16;
            const int rt = 2 * (p - rp);           // relative tile index of tile0
            const bf16_t* w0;
            const bf16_t* w1;
            if (kind == 0) {
                w0 = wqt + (size_t)(c0 + l15) * 192 + lg * 8;
                w1 = wqt + (size_t)(c1 + l15) * 192 + lg * 8;
            } else {
                int ofs = (kind == 2) ? 192 : 0;
                w0 = wkvt + (size_t)(ofs + c0 + l15) * 192 + lg * 8;
                w1 = wkvt + (size_t)(ofs + c1 + l15) * 192 + lg * 8;
            }
            bf16x8 b0[6], b1[6];
#pragma unroll
            for (int ks = 0; ks < 6; ks++) {
                b0[ks] = *(const bf16x8*)(w0 + ks * 32);
                b1[ks] = *(const bf16x8*)(w1 + ks * 32);
            }
            if (kind < 2) {
                const float* bp = (kind == 0) ? bqs : bkv;
                float4 q0 = *(const float4*)(bp + c0 + lg * 4);
                float4 q1 = *(const float4*)(bp + c1 + lg * 4);
                bf16_t* dbase = (kind == 0) ? qt : kt;
                bf16_t* d0 = dbase + ((size_t)lw * 12 + rt) * 784;
                bf16_t* d1 = d0 + 784;
#pragma unroll
                for (int mt = 0; mt < 4; mt++) {
                    int xr = mt * 16 + l15;
                    bf16x8 xf[6];
#pragma unroll
                    for (int ks = 0; ks < 6; ks++)
                        xf[ks] = *(const bf16x8*)(Xs + xr * 384 + SWZ(xr, ks * 64 + lg * 16));
                    f32x4 a0 = { q0.x, q0.y, q0.z, q0.w };
                    f32x4 a1 = { q1.x, q1.y, q1.z, q1.w };
#pragma unroll
                    for (int ks = 0; ks < 6; ks++) {
                        a0 = __builtin_amdgcn_mfma_f32_16x16x32_bf16(b0[ks], xf[ks], a0, 0, 0, 0);
                        a1 = __builtin_amdgcn_mfma_f32_16x16x32_bf16(b1[ks], xf[ks], a1, 0, 0, 0);
                    }
                    int tok = mt * 16 + l15;     // D col = token
                    if (tok < NTOK) {
                        bf16x4 s0 = { (bf16_t)a0[0], (bf16_t)a0[1], (bf16_t)a0[2], (bf16_t)a0[3] };
                        bf16x4 s1 = { (bf16_t)a1[0], (bf16_t)a1[1], (bf16_t)a1[2], (bf16_t)a1[3] };
                        *(bf16x4*)(d0 + tok * 16 + lg * 4) = s0;
                        *(bf16x4*)(d1 + tok * 16 + lg * 4) = s1;
                    }
                }
            } else {
                float v0b = bkv[192 + c0 + l15];
                float v1b = bkv[192 + c1 + l15];
                bf16_t* e0 = vt + ((size_t)lw * 192 + c0 + l15) * 56;
                bf16_t* e1 = vt + ((size_t)lw * 192 + c1 + l15) * 56;
#pragma unroll
                for (int mt = 0; mt < 4; mt++) {
                    int xr = mt * 16 + l15;
                    bf16x8 xf[6];
#pragma unroll
                    for (int ks = 0; ks < 6; ks++)
                        xf[ks] = *(const bf16x8*)(Xs + xr * 384 + SWZ(xr, ks * 64 + lg * 16));
                    f32x4 a0 = { v0b, v0b, v0b, v0b };
                    f32x4 a1 = { v1b, v1b, v1b, v1b };
#pragma unroll
                    for (int ks = 0; ks < 6; ks++) {
                        a0 = __builtin_amdgcn_mfma_f32_16x16x32_bf16(xf[ks], b0[ks], a0, 0, 0, 0);
                        a1 = __builtin_amdgcn_mfma_f32_16x16x32_bf16(xf[ks], b1[ks], a1, 0, 0, 0);
                    }
                    int t0 = mt * 16 + lg * 4;   // D row = token
                    if (t0 < NTOK) {
                        bf16x4 s0 = { (bf16_t)a0[0], (bf16_t)a0[1], (bf16_t)a0[2], (bf16_t)a0[3] };
                        bf16x4 s1 = { (bf16_t)a1[0], (bf16_t)a1[1], (bf16_t)a1[2], (bf16_t)a1[3] };
                        *(bf16x4*)(e0 + t0) = s0;
                        *(bf16x4*)(e1 + t0) = s1;
                    }
                }
            }
        }
        __syncthreads();
    }
}

// ---------------- Kernel B: attention + out-projection ----------------
__global__ __launch_bounds__(512, 4) void attn2_kernel(
    const bf16_t* __restrict__ qt, const bf16_t* __restrict__ kt, const bf16_t* __restrict__ vt,
    const bf16_t* __restrict__ wpt, const float* __restrict__ bproj,
    const float* __restrict__ tbl, float* __restrict__ out, int base)
{
    __shared__ __align__(16) unsigned char smem[73728];
    unsigned char* Ks = smem;            // [64][384B] K[token][chan]
    unsigned char* Vt = smem + 24576;    // [192][128B] V^T[chan][token]
    unsigned char* Os = smem + 49152;    // [64][384B] O[token][chan]

    const int tid = threadIdx.x;
    const int wid = tid >> 6;
    const int lane = tid & 63;
    const int l15 = lane & 15;
    const int lg = lane >> 4;
    const int t0i = blockIdx.x;
    const int bl = (t0i & ~63) | ((t0i & 7) << 3) | ((t0i >> 3) & 7);  // XCD-cluster swizzle
    const int b = base + bl;
    const int widx = b & 63;

    const bf16_t* kg = kt + (size_t)bl * QT_WIN;
    const bf16_t* vg = vt + (size_t)bl * VT_WIN;
    const bf16_t* qg = qt + (size_t)bl * QT_WIN;

    // stage K: 49 toks x 24 half-tile chunks (8 chans = 16B each)
    for (int idx = tid; idx < 1176; idx += 512) {
        int t = idx / 24, c8 = idx % 24;
        bf16x8 v = *(const bf16x8*)(kg + ((size_t)(c8 >> 1) * 49 + t) * 16 + (c8 & 1) * 8);
        *(bf16x8*)(Ks + t * 384 + SWZ(t, c8 * 16)) = v;
    }
    for (int idx = tid; idx < 720; idx += 512)
        *(unsigned long long*)(Ks + 49 * 384 + idx * 8) = 0ULL;
    // stage V: direct copy [chan][tok], zero pads (toks 49..63)
    uint4 zz = { 0u, 0u, 0u, 0u };
    const bf16x8 z8 = __builtin_bit_cast(bf16x8, zz);
    for (int idx = tid; idx < 1536; idx += 512) {
        int ch = idx >> 3, c = idx & 7;
        bf16x8 v;
        if (c < 6) v = *(const bf16x8*)(vg + (size_t)ch * 56 + c * 8);
        else if (c == 6) {
            bf16x8 r = *(const bf16x8*)(vg + (size_t)ch * 56 + 48);
            v = z8; v[0] = r[0];     // keep tok 48 only
        } else v = z8;
        *(bf16x8*)(Vt + ch * 128 + SWZ(ch, c * 16)) = v;
    }
    // prefetch Q fragments for this wave's 3 units
    bf16x8 qf[3];
#pragma unroll
    for (int i3 = 0; i3 < 3; i3++) {
        int u = wid + 8 * i3, h = u >> 2, qtl = u & 3;
        int qrow = qtl * 16 + l15;
        qf[i3] = (qrow < NTOK)
            ? *(const bf16x8*)(qg + ((size_t)(h * 2 + (lg >> 1)) * 49 + qrow) * 16 + (lg & 1) * 8)
            : z8;
    }
    // prefetch unit-0 bias+mask table rows
    float4 tb0[4], tb1[4];
    auto tload = [&](int i3, float4* dst) {
        int u = wid + 8 * i3, h = u >> 2, qtl = u & 3;
        int q = qtl * 16 + l15;
        if (q < NTOK) {
            const float* tp = tbl + (((size_t)(widx * 6 + h) * 49 + q) << 6) + lg * 4;
#pragma unroll
            for (int f = 0; f < 4; f++) dst[f] = *(const float4*)(tp + f * 16);
        } else {
#pragma unroll
            for (int f = 0; f < 4; f++) dst[f] = make_float4(0.f, 0.f, 0.f, 0.f);
        }
    };
    tload(0, tb0);
    __syncthreads();

    // ---- attention: 24 (head,qtile) units, 3 per wave ----
#pragma unroll
    for (int i3 = 0; i3 < 3; i3++) {
        int u = wid + 8 * i3;
        int h = u >> 2, qtl = u & 3;
        bf16x8 qfr = qf[i3];
        if (i3 < 2) tload(i3 + 1, (i3 & 1) ? tb0 : tb1);
        f32x4 s[4];
#pragma unroll
        for (int f = 0; f < 4; f++) {
            int kr = f * 16 + l15;
            bf16x8 kfr = *(const bf16x8*)(Ks + kr * 384 + SWZ(kr, h * 64 + lg * 16));
            f32x4 z = { 0.f, 0.f, 0.f, 0.f };
            s[f] = __builtin_amdgcn_mfma_f32_16x16x32_bf16(kfr, qfr, z, 0, 0, 0);
        }
        int q = qtl * 16 + l15;
        bool qok = (q < NTOK);
        const float4* tbc = (i3 & 1) ? tb1 : tb0;
#pragma unroll
        for (int f = 0; f < 4; f++) {
            if (qok) {
                s[f][0] += tbc[f].x; s[f][1] += tbc[f].y; s[f][2] += tbc[f].z; s[f][3] += tbc[f].w;
            } else {
#pragma unroll
                for (int j = 0; j < 4; j++) { int k = f * 16 + lg * 4 + j; if (k >= NTOK) s[f][j] = -1e30f; }
            }
        }
        // softmax over k (exp2 domain)
        float m = s[0][0];
#pragma unroll
        for (int f = 0; f < 4; f++)
#pragma unroll
            for (int j = 0; j < 4; j++) m = fmaxf(m, s[f][j]);
        m = fmaxf(m, __shfl_xor(m, 16));
        m = fmaxf(m, __shfl_xor(m, 32));
        float t = 0.f;
#pragma unroll
        for (int f = 0; f < 4; f++)
#pragma unroll
            for (int j = 0; j < 4; j++) { s[f][j] = __builtin_amdgcn_exp2f(s[f][j] - m); t += s[f][j]; }
        t += __shfl_xor(t, 16);
        t += __shfl_xor(t, 32);
        float inv = __builtin_amdgcn_rcpf(t);
        // pack P (unnormalized), reshuffle into PV B-operand layout
        unsigned Wp[8];
#pragma unroll
        for (int f = 0; f < 4; f++) {
            Wp[f * 2 + 0] = pk2(s[f][0], s[f][1]);
            Wp[f * 2 + 1] = pk2(s[f][2], s[f][3]);
        }
        bf16x8 pa[2];
#pragma unroll
        for (int ks2 = 0; ks2 < 2; ks2++) {
            unsigned pw[4];
#pragma unroll
            for (int p = 0; p < 4; p++) {
                int src = l15 + 16 * (((lg & 1) << 1) | (p >> 1));
                unsigned v0 = (unsigned)__shfl((int)Wp[(2 * ks2) * 2 + (p & 1)], src, 64);
                unsigned v1 = (unsigned)__shfl((int)Wp[(2 * ks2 + 1) * 2 + (p & 1)], src, 64);
                pw[p] = (lg & 2) ? v1 : v0;
            }
            uint4 pp = { pw[0], pw[1], pw[2], pw[3] };
            pa[ks2] = __builtin_bit_cast(bf16x8, pp);
        }
        // PV (swapped): D[chan][q]; normalize post-hoc
#pragma unroll
        for (int dt = 0; dt < 2; dt++) {
            f32x4 acc = { 0.f, 0.f, 0.f, 0.f };
#pragma unroll
            for (int ks2 = 0; ks2 < 2; ks2++) {
                int vr = h * 32 + dt * 16 + l15;
                bf16x8 vfr = *(const bf16x8*)(Vt + vr * 128 + SWZ(vr, ks2 * 64 + lg * 16));
                acc = __builtin_amdgcn_mfma_f32_16x16x32_bf16(vfr, pa[ks2], acc, 0, 0, 0);
            }
            int orow = qtl * 16 + l15;
            bf16x4 op4 = { (bf16_t)(acc[0] * inv), (bf16_t)(acc[1] * inv),
                           (bf16_t)(acc[2] * inv), (bf16_t)(acc[3] * inv) };
            *(bf16x4*)(Os + orow * 384 + SWZ(orow, h * 64 + dt * 32 + lg * 8)) = op4;
        }
    }
    __syncthreads();

    // ---- out projection (swapped), float4 global stores; 6 units/wave ----
    {
        float* op = out + (size_t)b * (NTOK * CCH);
        bf16x8 bfr[6];
        float4 b4 = { 0.f, 0.f, 0.f, 0.f };
        int prev_nt = -1;
        for (int i = 0; i < 6; i++) {
            int u = wid * 6 + i;
            int nt = u >> 2, mt = u & 3;
            if (nt != prev_nt) {
                prev_nt = nt;
                const bf16_t* wr = wpt + (size_t)(nt * 16 + l15) * 192 + lg * 8;
#pragma unroll
                for (int ks = 0; ks < 6; ks++) bfr[ks] = *(const bf16x8*)(wr + ks * 32);
                b4 = *(const float4*)(bproj + nt * 16 + lg * 4);
            }
            int orow = mt * 16 + l15;
            f32x4 acc = { b4.x, b4.y, b4.z, b4.w };
#pragma unroll
            for (int ks = 0; ks < 6; ks++) {
                bf16x8 of = *(const bf16x8*)(Os + orow * 384 + SWZ(orow, ks * 64 + lg * 16));
                acc = __builtin_amdgcn_mfma_f32_16x16x32_bf16(bfr[ks], of, acc, 0, 0, 0);
            }
            if (orow < NTOK) {
                float4 st = { acc[0], acc[1], acc[2], acc[3] };
                *(float4*)(op + orow * 192 + nt * 16 + lg * 4) = st;
            }
        }
    }
}

// ---------------- Monolithic fallback (round-4 kernel, proven) ----------------
__global__ __launch_bounds__(512, 4) void wattn_mono(
    const float* __restrict__ xq, const float* __restrict__ mask,
    const float* __restrict__ bkv, const float* __restrict__ bproj,
    const bf16_t* __restrict__ wqt, const bf16_t* __restrict__ wkvt, const bf16_t* __restrict__ wpt,
    const float* __restrict__ bqs, const float* __restrict__ tbl,
    float* __restrict__ out, int mode)
{
    __shared__ __align__(16) unsigned char smem[73728];
    unsigned char* QsO = smem;
    unsigned char* Ks  = smem + 24576;
    unsigned char* Vt  = smem + 49152;

    const int tid = threadIdx.x;
    const int wid = tid >> 6;
    const int lane = tid & 63;
    const int l15 = lane & 15;
    const int lg = lane >> 4;
    const int t0 = blockIdx.x;
    const int b = (t0 & 0x1FC0) | ((t0 & 7) << 3) | ((t0 >> 3) & 7);
    const float* xp = xq + (size_t)b * (NTOK * CCH);
    const float LOG2E = 1.4426950408889634f;

    const int mtp = wid & 1;
    const int ntq = wid >> 1;
    bf16x8 xf[2][6];
#pragma unroll
    for (int e = 0; e < 2; e++) {
        int tok = (mtp * 2 + e) * 16 + l15;
        const float* xrow = xp + (size_t)tok * 192;
        bool ok = (tok < NTOK);
#pragma unroll
        for (int ks = 0; ks < 6; ks++) {
            float4 a = { 0.f, 0.f, 0.f, 0.f }, c = { 0.f, 0.f, 0.f, 0.f };
            if (ok) {
                a = *(const float4*)(xrow + ks * 32 + lg * 8);
                c = *(const float4*)(xrow + ks * 32 + lg * 8 + 4);
            }
            bf16x8 f = { (bf16_t)a.x, (bf16_t)a.y, (bf16_t)a.z, (bf16_t)a.w,
                         (bf16_t)c.x, (bf16_t)c.y, (bf16_t)c.z, (bf16_t)c.w };
            xf[e][ks] = f;
        }
    }
    for (int k9 = 0; k9 < 9; k9++) {
        int nt = ntq + 4 * k9;
        int kind = nt < 12 ? 0 : (nt < 24 ? 1 : 2);
        int ncol = (nt - (kind == 1 ? 12 : (kind == 2 ? 24 : 0))) * 16;
        const bf16_t* wr;
        if (kind == 0)      wr = wqt  + (size_t)(ncol + l15) * 192 + lg * 8;
        else if (kind == 1) wr = wkvt + (size_t)(ncol + l15) * 192 + lg * 8;
        else                wr = wkvt + (size_t)(192 + ncol + l15) * 192 + lg * 8;
        bf16x8 bfr[6];
#pragma unroll
        for (int ks = 0; ks < 6; ks++) bfr[ks] = *(const bf16x8*)(wr + ks * 32);
        if (kind < 2) {
            float4 b4 = (kind == 0) ? *(const float4*)(bqs + ncol + lg * 4)
                                    : *(const float4*)(bkv + ncol + lg * 4);
            f32x4 acc0 = { b4.x, b4.y, b4.z, b4.w }, acc1 = acc0;
#pragma unroll
            for (int ks = 0; ks < 6; ks++) {
                acc0 = __builtin_amdgcn_mfma_f32_16x16x32_bf16(bfr[ks], xf[0][ks], acc0, 0, 0, 0);
                acc1 = __builtin_amdgcn_mfma_f32_16x16x32_bf16(bfr[ks], xf[1][ks], acc1, 0, 0, 0);
            }
            unsigned char* dst = (kind == 0) ? QsO : Ks;
            int tr0 = (mtp * 2) * 16 + l15;
            int tr1 = tr0 + 16;
            bf16x4 p0 = { (bf16_t)acc0[0], (bf16_t)acc0[1], (bf16_t)acc0[2], (bf16_t)acc0[3] };
            bf16x4 p1 = { (bf16_t)acc1[0], (bf16_t)acc1[1], (bf16_t)acc1[2], (bf16_t)acc1[3] };
            *(bf16x4*)(dst + tr0 * 384 + SWZ(tr0, ncol * 2 + lg * 8)) = p0;
            *(bf16x4*)(dst + tr1 * 384 + SWZ(tr1, ncol * 2 + lg * 8)) = p1;
        } else {
            float bv = bkv[192 + ncol + l15];
            f32x4 acc0 = { bv, bv, bv, bv }, acc1 = acc0;
#pragma unroll
            for (int ks = 0; ks < 6; ks++) {
                acc0 = __builtin_amdgcn_mfma_f32_16x16x32_bf16(xf[0][ks], bfr[ks], acc0, 0, 0, 0);
                acc1 = __builtin_amdgcn_mfma_f32_16x16x32_bf16(xf[1][ks], bfr[ks], acc1, 0, 0, 0);
            }
            int vr = ncol + l15;
            bf16x4 v0 = { (bf16_t)acc0[0], (bf16_t)acc0[1], (bf16_t)acc0[2], (bf16_t)acc0[3] };
            bf16x4 v1 = { (bf16_t)acc1[0], (bf16_t)acc1[1], (bf16_t)acc1[2], (bf16_t)acc1[3] };
            *(bf16x4*)(Vt + vr * 128 + SWZ(vr, (mtp * 2) * 32 + lg * 8)) = v0;
            *(bf16x4*)(Vt + vr * 128 + SWZ(vr, (mtp * 2 + 1) * 32 + lg * 8)) = v1;
        }
    }
    __syncthreads();

    const int widx = b & 63;
    for (int i3 = 0; i3 < 3; i3++) {
        int u = wid + 8 * i3;
        int h = u >> 2, qtl = u & 3;
        int qrow = qtl * 16 + l15;
        bf16x8 qfr = *(const bf16x8*)(QsO + qrow * 384 + SWZ(qrow, h * 64 + lg * 16));
        f32x4 s[4];
#pragma unroll
        for (int f = 0; f < 4; f++) {
            int kr = f * 16 + l15;
            bf16x8 kfr = *(const bf16x8*)(Ks + kr * 384 + SWZ(kr, h * 64 + lg * 16));
            f32x4 z = { 0.f, 0.f, 0.f, 0.f };
            s[f] = __builtin_amdgcn_mfma_f32_16x16x32_bf16(kfr, qfr, z, 0, 0, 0);
        }
        int q = qtl * 16 + l15;
        bool qok = (q < NTOK);
        if (mode == 0) {
#pragma unroll
            for (int f = 0; f < 4; f++) {
                if (qok) {
                    float4 bm = *(const float4*)(tbl + (((size_t)(widx * 6 + h) * 49 + q) << 6) + f * 16 + lg * 4);
                    s[f][0] += bm.x; s[f][1] += bm.y; s[f][2] += bm.z; s[f][3] += bm.w;
                } else {
#pragma unroll
                    for (int j = 0; j < 4; j++) { int k = f * 16 + lg * 4 + j; if (k >= NTOK) s[f][j] = -1e30f; }
                }
            }
        } else if (mode == 1) {
#pragma unroll
            for (int f = 0; f < 4; f++) {
                if (qok) {
                    float4 b1 = *(const float4*)(tbl + (((size_t)(h * 49 + q)) << 6) + f * 16 + lg * 4);
                    float4 m1 = *(const float4*)(tbl + 18816 + (((size_t)(widx * 49 + q)) << 6) + f * 16 + lg * 4);
                    s[f][0] += b1.x + m1.x; s[f][1] += b1.y + m1.y;
                    s[f][2] += b1.z + m1.z; s[f][3] += b1.w + m1.w;
                } else {
#pragma unroll
                    for (int j = 0; j < 4; j++) { int k = f * 16 + lg * 4 + j; if (k >= NTOK) s[f][j] = -1e30f; }
                }
            }
        } else {
#pragma unroll
            for (int f = 0; f < 4; f++)
#pragma unroll
                for (int j = 0; j < 4; j++) {
                    int k = f * 16 + lg * 4 + j;
                    if (k >= NTOK) s[f][j] = -1e30f;
                    else if (qok)
                        s[f][j] += (tbl[h * 2401 + q * 49 + k] + mask[(size_t)widx * 2401 + q * 49 + k]) * LOG2E;
                }
        }
        float m = s[0][0];
#pragma unroll
        for (int f = 0; f < 4; f++)
#pragma unroll
            for (int j = 0; j < 4; j++) m = fmaxf(m, s[f][j]);
        m = fmaxf(m, __shfl_xor(m, 16));
        m = fmaxf(m, __shfl_xor(m, 32));
        float t = 0.f;
#pragma unroll
        for (int f = 0; f < 4; f++)
#pragma unroll
            for (int j = 0; j < 4; j++) { s[f][j] = __builtin_amdgcn_exp2f(s[f][j] - m); t += s[f][j]; }
        t += __shfl_xor(t, 16);
        t += __shfl_xor(t, 32);
        float inv = __builtin_amdgcn_rcpf(t);
        unsigned Wp[8];
#pragma unroll
        for (int f = 0; f < 4; f++) {
            Wp[f * 2 + 0] = pk2(s[f][0], s[f][1]);
            Wp[f * 2 + 1] = pk2(s[f][2], s[f][3]);
        }
        bf16x8 pa[2];
#pragma unroll
        for (int ks2 = 0; ks2 < 2; ks2++) {
            unsigned pw[4];
#pragma unroll
            for (int p = 0; p < 4; p++) {
                int src = l15 + 16 * (((lg & 1) << 1) | (p >> 1));
                unsigned v0 = (unsigned)__shfl((int)Wp[(2 * ks2) * 2 + (p & 1)], src, 64);
                unsigned v1 = (unsigned)__shfl((int)Wp[(2 * ks2 + 1) * 2 + (p & 1)], src, 64);
                pw[p] = (lg & 2) ? v1 : v0;
            }
            uint4 pp = { pw[0], pw[1], pw[2], pw[3] };
            pa[ks2] = __builtin_bit_cast(bf16x8, pp);
        }
#pragma unroll
        for (int dt = 0; dt < 2; dt++) {
            f32x4 acc = { 0.f, 0.f, 0.f, 0.f };
#pragma unroll
            for (int ks2 = 0; ks2 < 2; ks2++) {
                int vr = h * 32 + dt * 16 + l15;
                bf16x8 vfr = *(const bf16x8*)(Vt + vr * 128 + SWZ(vr, ks2 * 64 + lg * 16));
                acc = __builtin_amdgcn_mfma_f32_16x16x32_bf16(vfr, pa[ks2], acc, 0, 0, 0);
            }
            int orow = qtl * 16 + l15;
            bf16x4 op4 = { (bf16_t)(acc[0] * inv), (bf16_t)(acc[1] * inv),
                           (bf16_t)(acc[2] * inv), (bf16_t)(acc[3] * inv) };
            *(bf16x4*)(QsO + orow * 384 + SWZ(orow, h * 64 + dt * 32 + lg * 8)) = op4;
        }
    }
    __syncthreads();

    {
        float* op = out + (size_t)b * (NTOK * CCH);
        bf16x8 bfr[6];
        float4 b4 = { 0.f, 0.f, 0.f, 0.f };
        int prev_nt = -1;
        for (int i = 0; i < 6; i++) {
            int u = wid * 6 + i;
            int nt = u >> 2, mt = u & 3;
            if (nt != prev_nt) {
                prev_nt = nt;
                const bf16_t* wr = wpt + (size_t)(nt * 16 + l15) * 192 + lg * 8;
#pragma unroll
                for (int ks = 0; ks < 6; ks++) bfr[ks] = *(const bf16x8*)(wr + ks * 32);
                b4 = *(const float4*)(bproj + nt * 16 + lg * 4);
            }
            int orow = mt * 16 + l15;
            f32x4 acc = { b4.x, b4.y, b4.z, b4.w };
#pragma unroll
            for (int ks = 0; ks < 6; ks++) {
                bf16x8 of = *(const bf16x8*)(QsO + orow * 384 + SWZ(orow, ks * 64 + lg * 16));
                acc = __builtin_amdgcn_mfma_f32_16x16x32_bf16(bfr[ks], of, acc, 0, 0, 0);
            }
            if (orow < NTOK) {
                float4 st = { acc[0], acc[1], acc[2], acc[3] };
                *(float4*)(op + orow * 192 + nt * 16 + lg * 4) = st;
            }
        }
    }
}

extern "C" void kernel_launch(void* const* d_in, const int* in_sizes, int n_in,
                              void* d_out, int out_size, void* d_ws, size_t ws_size,
                              hipStream_t stream) {
    const float* xq    = (const float*)d_in[0];
    const float* mask  = (const float*)d_in[1];
    const float* Wq    = (const float*)d_in[2];
    const float* bq    = (const float*)d_in[3];
    const float* Wkv   = (const float*)d_in[4];
    const float* bkv   = (const float*)d_in[5];
    const float* Wproj = (const float*)d_in[6];
    const float* bproj = (const float*)d_in[7];
    const float* btab  = (const float*)d_in[8];
    const int*   rel   = (const int*)d_in[9];
    float* out = (float*)d_out;

    char* ws = (char*)d_ws;
    bf16_t* wqt  = (bf16_t*)(ws + WS_WQT);
    bf16_t* wkvt = (bf16_t*)(ws + WS_WKVT);
    bf16_t* wpt  = (bf16_t*)(ws + WS_WPT);
    float*  bqs  = (float*)(ws + WS_BQS);
    float*  tbl  = (float*)(ws + WS_TBL);

    size_t need0 = (size_t)WS_TBL + 1204224u * 4u;
    size_t need1 = (size_t)WS_TBL + 219520u * 4u;
    int mode = (ws_size >= need0) ? 0 : (ws_size >= need1 ? 1 : 2);

    long tblN = (mode == 0) ? 1204224L : (mode == 1 ? 219520L : 14406L);
    long prep_elems = 147648L + tblN;
    int prep_blocks = (int)((prep_elems + 255) / 256);
    prep_kernel<<<prep_blocks, 256, 0, stream>>>(Wq, bq, Wkv, Wproj, btab, rel, mask,
                                                 wqt, wkvt, wpt, bqs, tbl, mode);

    size_t avail = (ws_size > (size_t)WS_QKV) ? ws_size - (size_t)WS_QKV : 0;
    long w_c_l = (long)(avail / QKV_BYTES_PER_WIN) & ~63L;
    int w_c = (int)(w_c_l > 8192 ? 8192 : w_c_l);

    if (w_c >= 64 && mode == 0) {
        bf16_t* qtb = (bf16_t*)(ws + WS_QKV);
        bf16_t* ktb = qtb + (size_t)w_c * QT_WIN;
        bf16_t* vtb = ktb + (size_t)w_c * QT_WIN;
        for (int base = 0; base < 8192; base += w_c) {
            int n = (8192 - base) < w_c ? (8192 - base) : w_c;
            qkv2_kernel<<<n / WPB, 512, 0, stream>>>(xq, bkv, wqt, wkvt, bqs, qtb, ktb, vtb, base);
            attn2_kernel<<<n, 512, 0, stream>>>(qtb, ktb, vtb, wpt, bproj, tbl, out, base);
        }
    } else {
        wattn_mono<<<8192, 512, 0, stream>>>(xq, mask, bkv, bproj, wqt, wkvt, wpt,
                                             bqs, tbl, out, mode);
    }
}

// Round 8
// 658.882 us; speedup vs baseline: 1.3869x; 1.0209x over previous
//
#include <hip/hip_runtime.h>

// WindowAttention for MI355X (gfx950) — round 8.
// Kernel A (qkv3): software-pipelined QKV GEMM — 2-window phases, balanced
//   (pair,window) units, reg-prefetch of next phase's X (T14 async-STAGE).
// Kernel B (attn2): attention + out-proj from tiled QKV (unchanged, proven).
// B_=8192 windows, N=49 tokens, C=192, H=6 heads, dh=32, NW=64 masks.

#define NTOK 49
#define CCH 192

typedef __bf16 bf16_t;
typedef bf16_t bf16x8 __attribute__((ext_vector_type(8)));
typedef bf16_t bf16x4 __attribute__((ext_vector_type(4)));
typedef bf16_t bf16x2 __attribute__((ext_vector_type(2)));
typedef float f32x4 __attribute__((ext_vector_type(4)));

// ws byte offsets
#define WS_WQT   0         // 192*192 bf16, pre-scaled by dh^-0.5 * log2e
#define WS_WKVT  73728     // 384*192 bf16
#define WS_WPT   221184    // 192*192 bf16
#define WS_BQS   294912    // 192 f32 pre-scaled q-bias
#define WS_TBL   295680    // bias/mask tables (mode-dependent, log2e-scaled)
#define WS_QKV   5112576   // QKV buffers after mode-0 table
#define QT_WIN   9408      // elems per window of tiled Q (12*49*16); K same
#define VT_WIN   10752     // elems per window of tiled V (192*56)
#define QKV_BYTES_PER_WIN 59136   // (9408*2 + 10752) * 2B

#define SWZ(row, off) ((off) ^ (((row) & 7) << 4))

__device__ __forceinline__ unsigned pk2(float a, float b) {
    bf16x2 w = { (bf16_t)a, (bf16_t)b };
    return __builtin_bit_cast(unsigned, w);
}

__global__ void prep_kernel(const float* __restrict__ Wq, const float* __restrict__ bq,
                            const float* __restrict__ Wkv, const float* __restrict__ Wproj,
                            const float* __restrict__ btab, const int* __restrict__ rel,
                            const float* __restrict__ mask,
                            bf16_t* __restrict__ wqt, bf16_t* __restrict__ wkvt,
                            bf16_t* __restrict__ wpt, float* __restrict__ bqs,
                            float* __restrict__ tbl, int mode) {
    const float SC  = 0.2550718212080052f;   // dh^-0.5 * log2e
    const float L2E = 1.4426950408889634f;
    long i = (long)blockIdx.x * 256 + threadIdx.x;
    if (i < 36864) { int n = i / 192, k = i % 192; wqt[i] = (bf16_t)(Wq[k * 192 + n] * SC); return; }
    i -= 36864;
    if (i < 73728) { int n = i / 192, k = i % 192; wkvt[i] = (bf16_t)Wkv[k * 384 + n]; return; }
    i -= 73728;
    if (i < 36864) { int n = i / 192, k = i % 192; wpt[i] = (bf16_t)Wproj[k * 192 + n]; return; }
    i -= 36864;
    if (i < 192) { bqs[i] = bq[i] * SC; return; }
    i -= 192;
    if (mode == 0) {            // presummed [64][6][49][64], log2e-scaled, pad=-1e30
        if (i < 1204224) {
            int c = i & 63; long r = i >> 6; int q = r % 49; r /= 49; int h = r % 6; int w = r / 6;
            tbl[i] = (c < 49) ? (btab[rel[q * 49 + c] * 6 + h] + mask[(size_t)w * 2401 + q * 49 + c]) * L2E
                              : -1e30f;
        }
    } else if (mode == 1) {
        if (i < 18816) { int c = i & 63; int r = i >> 6; int q = r % 49; int h = r / 49;
            tbl[i] = (c < 49) ? btab[rel[q * 49 + c] * 6 + h] * L2E : 0.f; return; }
        i -= 18816;
        if (i < 200704) { int c = i & 63; long r = i >> 6; int q = r % 49; int w = r / 49;
            tbl[18816 + i] = (c < 49) ? mask[(size_t)w * 2401 + q * 49 + c] * L2E : -1e30f; }
    } else {
        if (i < 14406) { int h = i / 2401, rc = i % 2401; tbl[i] = btab[rel[rc] * 6 + h]; }
    }
}

// ---------------- Kernel A: pipelined QKV projection (qkv3) ----------------
// Block = 16 windows, 8 phases of 2 windows. 36 (pair,win) units per phase,
// pair-major (u>>1 = pair, u&1 = win) so consecutive units share weights.
// Waves 0-3: 5 units, waves 4-7: 4 units.
__global__ __launch_bounds__(512, 4) void qkv3_kernel(
    const float* __restrict__ xq, const float* __restrict__ bkv,
    const bf16_t* __restrict__ wqt, const bf16_t* __restrict__ wkvt,
    const float* __restrict__ bqs,
    bf16_t* __restrict__ qt, bf16_t* __restrict__ kt, bf16_t* __restrict__ vt,
    int base)
{
    __shared__ __align__(16) unsigned char Xs[2][24576];   // [64][384B] bf16, swizzled
    const int tid = threadIdx.x;
    const int wid = tid >> 6;
    const int lane = tid & 63;
    const int l15 = lane & 15;
    const int lg = lane >> 4;
    const int lw0 = blockIdx.x * 16;     // first local window of this block

    bf16x4 st[10];                        // staged bf16 X for next 2 windows
    // prefetch: load + convert windows {2ph, 2ph+1} (global, fp32 -> bf16 regs)
    auto prefetch = [&](int ph) {
#pragma unroll
        for (int j = 0; j < 10; j++) {
            int g = j * 512 + tid;
            if (g < 4704) {
                int win = g / 2352, rem = g % 2352, r = rem / 48, c4 = rem % 48;
                const float* xp = xq + (size_t)(base + lw0 + 2 * ph + win) * 9408 + r * 192 + c4 * 4;
                float4 v = *(const float4*)xp;
                st[j] = bf16x4{ (bf16_t)v.x, (bf16_t)v.y, (bf16_t)v.z, (bf16_t)v.w };
            }
        }
    };
    auto commit = [&]() {                 // staged regs -> LDS
#pragma unroll
        for (int j = 0; j < 10; j++) {
            int g = j * 512 + tid;
            if (g < 4704) {
                int win = g / 2352, rem = g % 2352, r = rem / 48, c4 = rem % 48;
                *(bf16x4*)(Xs[win] + r * 384 + SWZ(r, c4 * 8)) = st[j];
            }
        }
    };

    prefetch(0);
    // zero pad rows 49..63 of both buffers (compute never overwrites them)
    for (int idx = tid; idx < 1440; idx += 512) {
        int win = idx / 720, o = idx % 720;
        *(unsigned long long*)(Xs[win] + 49 * 384 + o * 8) = 0ULL;
    }
    commit();

    const int u0 = (wid < 4) ? 5 * wid : 20 + 4 * (wid - 4);
    const int nu = (wid < 4) ? 5 : 4;

    for (int ph = 0; ph < 8; ph++) {
        __syncthreads();                  // staged X visible
        if (ph < 7) prefetch(ph + 1);     // issue next loads before compute

        int prevPair = -1;
        bf16x8 b0[6], b1[6];
        float4 q0 = {0.f,0.f,0.f,0.f}, q1 = {0.f,0.f,0.f,0.f};
        float v0b = 0.f, v1b = 0.f;
        int kind = 0, c0 = 0, rt = 0;
        for (int iu = 0; iu < nu; iu++) {
            int u = u0 + iu;
            int pair = u >> 1, win = u & 1;
            if (pair != prevPair) {
                prevPair = pair;
                kind = (pair < 6) ? 0 : (pair < 12 ? 1 : 2);
                const int rp = (kind == 0) ? 0 : (kind == 1 ? 6 : 12);
                c0 = (pair - rp) * 32;
                rt = 2 * (pair - rp);
                const bf16_t* w0p;
                const bf16_t* w1p;
                if (kind == 0) {
                    w0p = wqt + (size_t)(c0 + l15) * 192 + lg * 8;
                    w1p = wqt + (size_t)(c0 + 16 + l15) * 192 + lg * 8;
                } else {
                    int ofs = (kind == 2) ? 192 : 0;
                    w0p = wkvt + (size_t)(ofs + c0 + l15) * 192 + lg * 8;
                    w1p = wkvt + (size_t)(ofs + c0 + 16 + l15) * 192 + lg * 8;
                }
#pragma unroll
                for (int ks = 0; ks < 6; ks++) {
                    b0[ks] = *(const bf16x8*)(w0p + ks * 32);
                    b1[ks] = *(const bf16x8*)(w1p + ks * 32);
                }
                if (kind < 2) {
                    const float* bp = (kind == 0) ? bqs : bkv;
                    q0 = *(const float4*)(bp + c0 + lg * 4);
                    q1 = *(const float4*)(bp + c0 + 16 + lg * 4);
                } else {
                    v0b = bkv[192 + c0 + l15];
                    v1b = bkv[192 + c0 + 16 + l15];
                }
            }
            const int lw = lw0 + 2 * ph + win;
            const unsigned char* Xw = Xs[win];
            if (kind < 2) {
                bf16_t* dbase = (kind == 0) ? qt : kt;
                bf16_t* d0 = dbase + ((size_t)lw * 12 + rt) * 784;
                bf16_t* d1 = d0 + 784;
#pragma unroll
                for (int mt = 0; mt < 4; mt++) {
                    int xr = mt * 16 + l15;
                    bf16x8 xf[6];
#pragma unroll
                    for (int ks = 0; ks < 6; ks++)
                        xf[ks] = *(const bf16x8*)(Xw + xr * 384 + SWZ(xr, ks * 64 + lg * 16));
                    f32x4 a0 = { q0.x, q0.y, q0.z, q0.w };
                    f32x4 a1 = { q1.x, q1.y, q1.z, q1.w };
#pragma unroll
                    for (int ks = 0; ks < 6; ks++) {
                        a0 = __builtin_amdgcn_mfma_f32_16x16x32_bf16(b0[ks], xf[ks], a0, 0, 0, 0);
                        a1 = __builtin_amdgcn_mfma_f32_16x16x32_bf16(b1[ks], xf[ks], a1, 0, 0, 0);
                    }
                    int tok = mt * 16 + l15;     // D col = token
                    if (tok < NTOK) {
                        bf16x4 s0 = { (bf16_t)a0[0], (bf16_t)a0[1], (bf16_t)a0[2], (bf16_t)a0[3] };
                        bf16x4 s1 = { (bf16_t)a1[0], (bf16_t)a1[1], (bf16_t)a1[2], (bf16_t)a1[3] };
                        *(bf16x4*)(d0 + tok * 16 + lg * 4) = s0;
                        *(bf16x4*)(d1 + tok * 16 + lg * 4) = s1;
                    }
                }
            } else {
                bf16_t* e0 = vt + ((size_t)lw * 192 + c0 + l15) * 56;
                bf16_t* e1 = e0 + 16 * 56;
#pragma unroll
                for (int mt = 0; mt < 4; mt++) {
                    int xr = mt * 16 + l15;
                    bf16x8 xf[6];
#pragma unroll
                    for (int ks = 0; ks < 6; ks++)
                        xf[ks] = *(const bf16x8*)(Xw + xr * 384 + SWZ(xr, ks * 64 + lg * 16));
                    f32x4 a0 = { v0b, v0b, v0b, v0b };
                    f32x4 a1 = { v1b, v1b, v1b, v1b };
#pragma unroll
                    for (int ks = 0; ks < 6; ks++) {
                        a0 = __builtin_amdgcn_mfma_f32_16x16x32_bf16(xf[ks], b0[ks], a0, 0, 0, 0);
                        a1 = __builtin_amdgcn_mfma_f32_16x16x32_bf16(xf[ks], b1[ks], a1, 0, 0, 0);
                    }
                    int t0 = mt * 16 + lg * 4;   // D row = token
                    if (t0 < NTOK) {
                        bf16x4 s0 = { (bf16_t)a0[0], (bf16_t)a0[1], (bf16_t)a0[2], (bf16_t)a0[3] };
                        bf16x4 s1 = { (bf16_t)a1[0], (bf16_t)a1[1], (bf16_t)a1[2], (bf16_t)a1[3] };
                        *(bf16x4*)(e0 + t0) = s0;
                        *(bf16x4*)(e1 + t0) = s1;
                    }
                }
            }
        }
        if (ph < 7) {
            __syncthreads();              // all reads of Xs done
            commit();                     // write next 2 windows
        }
    }
}

// ---------------- Kernel B: attention + out-projection ----------------
__global__ __launch_bounds__(512, 4) void attn2_kernel(
    const bf16_t* __restrict__ qt, const bf16_t* __restrict__ kt, const bf16_t* __restrict__ vt,
    const bf16_t* __restrict__ wpt, const float* __restrict__ bproj,
    const float* __restrict__ tbl, float* __restrict__ out, int base)
{
    __shared__ __align__(16) unsigned char smem[73728];
    unsigned char* Ks = smem;            // [64][384B] K[token][chan]
    unsigned char* Vt = smem + 24576;    // [192][128B] V^T[chan][token]
    unsigned char* Os = smem + 49152;    // [64][384B] O[token][chan]

    const int tid = threadIdx.x;
    const int wid = tid >> 6;
    const int lane = tid & 63;
    const int l15 = lane & 15;
    const int lg = lane >> 4;
    const int t0i = blockIdx.x;
    const int bl = (t0i & ~63) | ((t0i & 7) << 3) | ((t0i >> 3) & 7);  // XCD-cluster swizzle
    const int b = base + bl;
    const int widx = b & 63;

    const bf16_t* kg = kt + (size_t)bl * QT_WIN;
    const bf16_t* vg = vt + (size_t)bl * VT_WIN;
    const bf16_t* qg = qt + (size_t)bl * QT_WIN;

    // stage K: 49 toks x 24 half-tile chunks (8 chans = 16B each)
    for (int idx = tid; idx < 1176; idx += 512) {
        int t = idx / 24, c8 = idx % 24;
        bf16x8 v = *(const bf16x8*)(kg + ((size_t)(c8 >> 1) * 49 + t) * 16 + (c8 & 1) * 8);
        *(bf16x8*)(Ks + t * 384 + SWZ(t, c8 * 16)) = v;
    }
    for (int idx = tid; idx < 720; idx += 512)
        *(unsigned long long*)(Ks + 49 * 384 + idx * 8) = 0ULL;
    // stage V: direct copy [chan][tok], zero pads (toks 49..63)
    uint4 zz = { 0u, 0u, 0u, 0u };
    const bf16x8 z8 = __builtin_bit_cast(bf16x8, zz);
    for (int idx = tid; idx < 1536; idx += 512) {
        int ch = idx >> 3, c = idx & 7;
        bf16x8 v;
        if (c < 6) v = *(const bf16x8*)(vg + (size_t)ch * 56 + c * 8);
        else if (c == 6) {
            bf16x8 r = *(const bf16x8*)(vg + (size_t)ch * 56 + 48);
            v = z8; v[0] = r[0];     // keep tok 48 only
        } else v = z8;
        *(bf16x8*)(Vt + ch * 128 + SWZ(ch, c * 16)) = v;
    }
    // prefetch Q fragments for this wave's 3 units
    bf16x8 qf[3];
#pragma unroll
    for (int i3 = 0; i3 < 3; i3++) {
        int u = wid + 8 * i3, h = u >> 2, qtl = u & 3;
        int qrow = qtl * 16 + l15;
        qf[i3] = (qrow < NTOK)
            ? *(const bf16x8*)(qg + ((size_t)(h * 2 + (lg >> 1)) * 49 + qrow) * 16 + (lg & 1) * 8)
            : z8;
    }
    // prefetch unit-0 bias+mask table rows
    float4 tb0[4], tb1[4];
    auto tload = [&](int i3, float4* dst) {
        int u = wid + 8 * i3, h = u >> 2, qtl = u & 3;
        int q = qtl * 16 + l15;
        if (q < NTOK) {
            const float* tp = tbl + (((size_t)(widx * 6 + h) * 49 + q) << 6) + lg * 4;
#pragma unroll
            for (int f = 0; f < 4; f++) dst[f] = *(const float4*)(tp + f * 16);
        } else {
#pragma unroll
            for (int f = 0; f < 4; f++) dst[f] = make_float4(0.f, 0.f, 0.f, 0.f);
        }
    };
    tload(0, tb0);
    __syncthreads();

    // ---- attention: 24 (head,qtile) units, 3 per wave ----
#pragma unroll
    for (int i3 = 0; i3 < 3; i3++) {
        int u = wid + 8 * i3;
        int h = u >> 2, qtl = u & 3;
        bf16x8 qfr = qf[i3];
        if (i3 < 2) tload(i3 + 1, (i3 & 1) ? tb0 : tb1);
        f32x4 s[4];
#pragma unroll
        for (int f = 0; f < 4; f++) {
            int kr = f * 16 + l15;
            bf16x8 kfr = *(const bf16x8*)(Ks + kr * 384 + SWZ(kr, h * 64 + lg * 16));
            f32x4 z = { 0.f, 0.f, 0.f, 0.f };
            s[f] = __builtin_amdgcn_mfma_f32_16x16x32_bf16(kfr, qfr, z, 0, 0, 0);
        }
        int q = qtl * 16 + l15;
        bool qok = (q < NTOK);
        const float4* tbc = (i3 & 1) ? tb1 : tb0;
#pragma unroll
        for (int f = 0; f < 4; f++) {
            if (qok) {
                s[f][0] += tbc[f].x; s[f][1] += tbc[f].y; s[f][2] += tbc[f].z; s[f][3] += tbc[f].w;
            } else {
#pragma unroll
                for (int j = 0; j < 4; j++) { int k = f * 16 + lg * 4 + j; if (k >= NTOK) s[f][j] = -1e30f; }
            }
        }
        // softmax over k (exp2 domain)
        float m = s[0][0];
#pragma unroll
        for (int f = 0; f < 4; f++)
#pragma unroll
            for (int j = 0; j < 4; j++) m = fmaxf(m, s[f][j]);
        m = fmaxf(m, __shfl_xor(m, 16));
        m = fmaxf(m, __shfl_xor(m, 32));
        float t = 0.f;
#pragma unroll
        for (int f = 0; f < 4; f++)
#pragma unroll
            for (int j = 0; j < 4; j++) { s[f][j] = __builtin_amdgcn_exp2f(s[f][j] - m); t += s[f][j]; }
        t += __shfl_xor(t, 16);
        t += __shfl_xor(t, 32);
        float inv = __builtin_amdgcn_rcpf(t);
        // pack P (unnormalized), reshuffle into PV B-operand layout
        unsigned Wp[8];
#pragma unroll
        for (int f = 0; f < 4; f++) {
            Wp[f * 2 + 0] = pk2(s[f][0], s[f][1]);
            Wp[f * 2 + 1] = pk2(s[f][2], s[f][3]);
        }
        bf16x8 pa[2];
#pragma unroll
        for (int ks2 = 0; ks2 < 2; ks2++) {
            unsigned pw[4];
#pragma unroll
            for (int p = 0; p < 4; p++) {
                int src = l15 + 16 * (((lg & 1) << 1) | (p >> 1));
                unsigned v0 = (unsigned)__shfl((int)Wp[(2 * ks2) * 2 + (p & 1)], src, 64);
                unsigned v1 = (unsigned)__shfl((int)Wp[(2 * ks2 + 1) * 2 + (p & 1)], src, 64);
                pw[p] = (lg & 2) ? v1 : v0;
            }
            uint4 pp = { pw[0], pw[1], pw[2], pw[3] };
            pa[ks2] = __builtin_bit_cast(bf16x8, pp);
        }
        // PV (swapped): D[chan][q]; normalize post-hoc
#pragma unroll
        for (int dt = 0; dt < 2; dt++) {
            f32x4 acc = { 0.f, 0.f, 0.f, 0.f };
#pragma unroll
            for (int ks2 = 0; ks2 < 2; ks2++) {
                int vr = h * 32 + dt * 16 + l15;
                bf16x8 vfr = *(const bf16x8*)(Vt + vr * 128 + SWZ(vr, ks2 * 64 + lg * 16));
                acc = __builtin_amdgcn_mfma_f32_16x16x32_bf16(vfr, pa[ks2], acc, 0, 0, 0);
            }
            int orow = qtl * 16 + l15;
            bf16x4 op4 = { (bf16_t)(acc[0] * inv), (bf16_t)(acc[1] * inv),
                           (bf16_t)(acc[2] * inv), (bf16_t)(acc[3] * inv) };
            *(bf16x4*)(Os + orow * 384 + SWZ(orow, h * 64 + dt * 32 + lg * 8)) = op4;
        }
    }
    __syncthreads();

    // ---- out projection (swapped), float4 global stores; 6 units/wave ----
    {
        float* op = out + (size_t)b * (NTOK * CCH);
        bf16x8 bfr[6];
        float4 b4 = { 0.f, 0.f, 0.f, 0.f };
        int prev_nt = -1;
        for (int i = 0; i < 6; i++) {
            int u = wid * 6 + i;
            int nt = u >> 2, mt = u & 3;
            if (nt != prev_nt) {
                prev_nt = nt;
                const bf16_t* wr = wpt + (size_t)(nt * 16 + l15) * 192 + lg * 8;
#pragma unroll
                for (int ks = 0; ks < 6; ks++) bfr[ks] = *(const bf16x8*)(wr + ks * 32);
                b4 = *(const float4*)(bproj + nt * 16 + lg * 4);
            }
            int orow = mt * 16 + l15;
            f32x4 acc = { b4.x, b4.y, b4.z, b4.w };
#pragma unroll
            for (int ks = 0; ks < 6; ks++) {
                bf16x8 of = *(const bf16x8*)(Os + orow * 384 + SWZ(orow, ks * 64 + lg * 16));
                acc = __builtin_amdgcn_mfma_f32_16x16x32_bf16(bfr[ks], of, acc, 0, 0, 0);
            }
            if (orow < NTOK) {
                float4 st = { acc[0], acc[1], acc[2], acc[3] };
                *(float4*)(op + orow * 192 + nt * 16 + lg * 4) = st;
            }
        }
    }
}

// ---------------- Monolithic fallback (round-4 kernel, proven) ----------------
__global__ __launch_bounds__(512, 4) void wattn_mono(
    const float* __restrict__ xq, const float* __restrict__ mask,
    const float* __restrict__ bkv, const float* __restrict__ bproj,
    const bf16_t* __restrict__ wqt, const bf16_t* __restrict__ wkvt, const bf16_t* __restrict__ wpt,
    const float* __restrict__ bqs, const float* __restrict__ tbl,
    float* __restrict__ out, int mode)
{
    __shared__ __align__(16) unsigned char smem[73728];
    unsigned char* QsO = smem;
    unsigned char* Ks  = smem + 24576;
    unsigned char* Vt  = smem + 49152;

    const int tid = threadIdx.x;
    const int wid = tid >> 6;
    const int lane = tid & 63;
    const int l15 = lane & 15;
    const int lg = lane >> 4;
    const int t0 = blockIdx.x;
    const int b = (t0 & 0x1FC0) | ((t0 & 7) << 3) | ((t0 >> 3) & 7);
    const float* xp = xq + (size_t)b * (NTOK * CCH);
    const float LOG2E = 1.4426950408889634f;

    const int mtp = wid & 1;
    const int ntq = wid >> 1;
    bf16x8 xf[2][6];
#pragma unroll
    for (int e = 0; e < 2; e++) {
        int tok = (mtp * 2 + e) * 16 + l15;
        const float* xrow = xp + (size_t)tok * 192;
        bool ok = (tok < NTOK);
#pragma unroll
        for (int ks = 0; ks < 6; ks++) {
            float4 a = { 0.f, 0.f, 0.f, 0.f }, c = { 0.f, 0.f, 0.f, 0.f };
            if (ok) {
                a = *(const float4*)(xrow + ks * 32 + lg * 8);
                c = *(const float4*)(xrow + ks * 32 + lg * 8 + 4);
            }
            bf16x8 f = { (bf16_t)a.x, (bf16_t)a.y, (bf16_t)a.z, (bf16_t)a.w,
                         (bf16_t)c.x, (bf16_t)c.y, (bf16_t)c.z, (bf16_t)c.w };
            xf[e][ks] = f;
        }
    }
    for (int k9 = 0; k9 < 9; k9++) {
        int nt = ntq + 4 * k9;
        int kind = nt < 12 ? 0 : (nt < 24 ? 1 : 2);
        int ncol = (nt - (kind == 1 ? 12 : (kind == 2 ? 24 : 0))) * 16;
        const bf16_t* wr;
        if (kind == 0)      wr = wqt  + (size_t)(ncol + l15) * 192 + lg * 8;
        else if (kind == 1) wr = wkvt + (size_t)(ncol + l15) * 192 + lg * 8;
        else                wr = wkvt + (size_t)(192 + ncol + l15) * 192 + lg * 8;
        bf16x8 bfr[6];
#pragma unroll
        for (int ks = 0; ks < 6; ks++) bfr[ks] = *(const bf16x8*)(wr + ks * 32);
        if (kind < 2) {
            float4 b4 = (kind == 0) ? *(const float4*)(bqs + ncol + lg * 4)
                                    : *(const float4*)(bkv + ncol + lg * 4);
            f32x4 acc0 = { b4.x, b4.y, b4.z, b4.w }, acc1 = acc0;
#pragma unroll
            for (int ks = 0; ks < 6; ks++) {
                acc0 = __builtin_amdgcn_mfma_f32_16x16x32_bf16(bfr[ks], xf[0][ks], acc0, 0, 0, 0);
                acc1 = __builtin_amdgcn_mfma_f32_16x16x32_bf16(bfr[ks], xf[1][ks], acc1, 0, 0, 0);
            }
            unsigned char* dst = (kind == 0) ? QsO : Ks;
            int tr0 = (mtp * 2) * 16 + l15;
            int tr1 = tr0 + 16;
            bf16x4 p0 = { (bf16_t)acc0[0], (bf16_t)acc0[1], (bf16_t)acc0[2], (bf16_t)acc0[3] };
            bf16x4 p1 = { (bf16_t)acc1[0], (bf16_t)acc1[1], (bf16_t)acc1[2], (bf16_t)acc1[3] };
            *(bf16x4*)(dst + tr0 * 384 + SWZ(tr0, ncol * 2 + lg * 8)) = p0;
            *(bf16x4*)(dst + tr1 * 384 + SWZ(tr1, ncol * 2 + lg * 8)) = p1;
        } else {
            float bv = bkv[192 + ncol + l15];
            f32x4 acc0 = { bv, bv, bv, bv }, acc1 = acc0;
#pragma unroll
            for (int ks = 0; ks < 6; ks++) {
                acc0 = __builtin_amdgcn_mfma_f32_16x16x32_bf16(xf[0][ks], bfr[ks], acc0, 0, 0, 0);
                acc1 = __builtin_amdgcn_mfma_f32_16x16x32_bf16(xf[1][ks], bfr[ks], acc1, 0, 0, 0);
            }
            int vr = ncol + l15;
            bf16x4 v0 = { (bf16_t)acc0[0], (bf16_t)acc0[1], (bf16_t)acc0[2], (bf16_t)acc0[3] };
            bf16x4 v1 = { (bf16_t)acc1[0], (bf16_t)acc1[1], (bf16_t)acc1[2], (bf16_t)acc1[3] };
            *(bf16x4*)(Vt + vr * 128 + SWZ(vr, (mtp * 2) * 32 + lg * 8)) = v0;
            *(bf16x4*)(Vt + vr * 128 + SWZ(vr, (mtp * 2 + 1) * 32 + lg * 8)) = v1;
        }
    }
    __syncthreads();

    const int widx = b & 63;
    for (int i3 = 0; i3 < 3; i3++) {
        int u = wid + 8 * i3;
        int h = u >> 2, qtl = u & 3;
        int qrow = qtl * 16 + l15;
        bf16x8 qfr = *(const bf16x8*)(QsO + qrow * 384 + SWZ(qrow, h * 64 + lg * 16));
        f32x4 s[4];
#pragma unroll
        for (int f = 0; f < 4; f++) {
            int kr = f * 16 + l15;
            bf16x8 kfr = *(const bf16x8*)(Ks + kr * 384 + SWZ(kr, h * 64 + lg * 16));
            f32x4 z = { 0.f, 0.f, 0.f, 0.f };
            s[f] = __builtin_amdgcn_mfma_f32_16x16x32_bf16(kfr, qfr, z, 0, 0, 0);
        }
        int q = qtl * 16 + l15;
        bool qok = (q < NTOK);
        if (mode == 0) {
#pragma unroll
            for (int f = 0; f < 4; f++) {
                if (qok) {
                    float4 bm = *(const float4*)(tbl + (((size_t)(widx * 6 + h) * 49 + q) << 6) + f * 16 + lg * 4);
                    s[f][0] += bm.x; s[f][1] += bm.y; s[f][2] += bm.z; s[f][3] += bm.w;
                } else {
#pragma unroll
                    for (int j = 0; j < 4; j++) { int k = f * 16 + lg * 4 + j; if (k >= NTOK) s[f][j] = -1e30f; }
                }
            }
        } else if (mode == 1) {
#pragma unroll
            for (int f = 0; f < 4; f++) {
                if (qok) {
                    float4 b1 = *(const float4*)(tbl + (((size_t)(h * 49 + q)) << 6) + f * 16 + lg * 4);
                    float4 m1 = *(const float4*)(tbl + 18816 + (((size_t)(widx * 49 + q)) << 6) + f * 16 + lg * 4);
                    s[f][0] += b1.x + m1.x; s[f][1] += b1.y + m1.y;
                    s[f][2] += b1.z + m1.z; s[f][3] += b1.w + m1.w;
                } else {
#pragma unroll
                    for (int j = 0; j < 4; j++) { int k = f * 16 + lg * 4 + j; if (k >= NTOK) s[f][j] = -1e30f; }
                }
            }
        } else {
#pragma unroll
            for (int f = 0; f < 4; f++)
#pragma unroll
                for (int j = 0; j < 4; j++) {
                    int k = f * 16 + lg * 4 + j;
                    if (k >= NTOK) s[f][j] = -1e30f;
                    else if (qok)
                        s[f][j] += (tbl[h * 2401 + q * 49 + k] + mask[(size_t)widx * 2401 + q * 49 + k]) * LOG2E;
                }
        }
        float m = s[0][0];
#pragma unroll
        for (int f = 0; f < 4; f++)
#pragma unroll
            for (int j = 0; j < 4; j++) m = fmaxf(m, s[f][j]);
        m = fmaxf(m, __shfl_xor(m, 16));
        m = fmaxf(m, __shfl_xor(m, 32));
        float t = 0.f;
#pragma unroll
        for (int f = 0; f < 4; f++)
#pragma unroll
            for (int j = 0; j < 4; j++) { s[f][j] = __builtin_amdgcn_exp2f(s[f][j] - m); t += s[f][j]; }
        t += __shfl_xor(t, 16);
        t += __shfl_xor(t, 32);
        float inv = __builtin_amdgcn_rcpf(t);
        unsigned Wp[8];
#pragma unroll
        for (int f = 0; f < 4; f++) {
            Wp[f * 2 + 0] = pk2(s[f][0], s[f][1]);
            Wp[f * 2 + 1] = pk2(s[f][2], s[f][3]);
        }
        bf16x8 pa[2];
#pragma unroll
        for (int ks2 = 0; ks2 < 2; ks2++) {
            unsigned pw[4];
#pragma unroll
            for (int p = 0; p < 4; p++) {
                int src = l15 + 16 * (((lg & 1) << 1) | (p >> 1));
                unsigned v0 = (unsigned)__shfl((int)Wp[(2 * ks2) * 2 + (p & 1)], src, 64);
                unsigned v1 = (unsigned)__shfl((int)Wp[(2 * ks2 + 1) * 2 + (p & 1)], src, 64);
                pw[p] = (lg & 2) ? v1 : v0;
            }
            uint4 pp = { pw[0], pw[1], pw[2], pw[3] };
            pa[ks2] = __builtin_bit_cast(bf16x8, pp);
        }
#pragma unroll
        for (int dt = 0; dt < 2; dt++) {
            f32x4 acc = { 0.f, 0.f, 0.f, 0.f };
#pragma unroll
            for (int ks2 = 0; ks2 < 2; ks2++) {
                int vr = h * 32 + dt * 16 + l15;
                bf16x8 vfr = *(const bf16x8*)(Vt + vr * 128 + SWZ(vr, ks2 * 64 + lg * 16));
                acc = __builtin_amdgcn_mfma_f32_16x16x32_bf16(vfr, pa[ks2], acc, 0, 0, 0);
            }
            int orow = qtl * 16 + l15;
            bf16x4 op4 = { (bf16_t)(acc[0] * inv), (bf16_t)(acc[1] * inv),
                           (bf16_t)(acc[2] * inv), (bf16_t)(acc[3] * inv) };
            *(bf16x4*)(QsO + orow * 384 + SWZ(orow, h * 64 + dt * 32 + lg * 8)) = op4;
        }
    }
    __syncthreads();

    {
        float* op = out + (size_t)b * (NTOK * CCH);
        bf16x8 bfr[6];
        float4 b4 = { 0.f, 0.f, 0.f, 0.f };
        int prev_nt = -1;
        for (int i = 0; i < 6; i++) {
            int u = wid * 6 + i;
            int nt = u >> 2, mt = u & 3;
            if (nt != prev_nt) {
                prev_nt = nt;
                const bf16_t* wr = wpt + (size_t)(nt * 16 + l15) * 192 + lg * 8;
#pragma unroll
                for (int ks = 0; ks < 6; ks++) bfr[ks] = *(const bf16x8*)(wr + ks * 32);
                b4 = *(const float4*)(bproj + nt * 16 + lg * 4);
            }
            int orow = mt * 16 + l15;
            f32x4 acc = { b4.x, b4.y, b4.z, b4.w };
#pragma unroll
            for (int ks = 0; ks < 6; ks++) {
                bf16x8 of = *(const bf16x8*)(QsO + orow * 384 + SWZ(orow, ks * 64 + lg * 16));
                acc = __builtin_amdgcn_mfma_f32_16x16x32_bf16(bfr[ks], of, acc, 0, 0, 0);
            }
            if (orow < NTOK) {
                float4 st = { acc[0], acc[1], acc[2], acc[3] };
                *(float4*)(op + orow * 192 + nt * 16 + lg * 4) = st;
            }
        }
    }
}

extern "C" void kernel_launch(void* const* d_in, const int* in_sizes, int n_in,
                              void* d_out, int out_size, void* d_ws, size_t ws_size,
                              hipStream_t stream) {
    const float* xq    = (const float*)d_in[0];
    const float* mask  = (const float*)d_in[1];
    const float* Wq    = (const float*)d_in[2];
    const float* bq    = (const float*)d_in[3];
    const float* Wkv   = (const float*)d_in[4];
    const float* bkv   = (const float*)d_in[5];
    const float* Wproj = (const float*)d_in[6];
    const float* bproj = (const float*)d_in[7];
    const float* btab  = (const float*)d_in[8];
    const int*   rel   = (const int*)d_in[9];
    float* out = (float*)d_out;

    char* ws = (char*)d_ws;
    bf16_t* wqt  = (bf16_t*)(ws + WS_WQT);
    bf16_t* wkvt = (bf16_t*)(ws + WS_WKVT);
    bf16_t* wpt  = (bf16_t*)(ws + WS_WPT);
    float*  bqs  = (float*)(ws + WS_BQS);
    float*  tbl  = (float*)(ws + WS_TBL);

    size_t need0 = (size_t)WS_TBL + 1204224u * 4u;
    size_t need1 = (size_t)WS_TBL + 219520u * 4u;
    int mode = (ws_size >= need0) ? 0 : (ws_size >= need1 ? 1 : 2);

    long tblN = (mode == 0) ? 1204224L : (mode == 1 ? 219520L : 14406L);
    long prep_elems = 147648L + tblN;
    int prep_blocks = (int)((prep_elems + 255) / 256);
    prep_kernel<<<prep_blocks, 256, 0, stream>>>(Wq, bq, Wkv, Wproj, btab, rel, mask,
                                                 wqt, wkvt, wpt, bqs, tbl, mode);

    size_t avail = (ws_size > (size_t)WS_QKV) ? ws_size - (size_t)WS_QKV : 0;
    long w_c_l = (long)(avail / QKV_BYTES_PER_WIN) & ~63L;
    int w_c = (int)(w_c_l > 8192 ? 8192 : w_c_l);

    if (w_c >= 64 && mode == 0) {
        bf16_t* qtb = (bf16_t*)(ws + WS_QKV);
        bf16_t* ktb = qtb + (size_t)w_c * QT_WIN;
        bf16_t* vtb = ktb + (size_t)w_c * QT_WIN;
        for (int base = 0; base < 8192; base += w_c) {
            int n = (8192 - base) < w_c ? (8192 - base) : w_c;
            qkv3_kernel<<<n / 16, 512, 0, stream>>>(xq, bkv, wqt, wkvt, bqs, qtb, ktb, vtb, base);
            attn2_kernel<<<n, 512, 0, stream>>>(qtb, ktb, vtb, wpt, bproj, tbl, out, base);
        }
    } else {
        wattn_mono<<<8192, 512, 0, stream>>>(xq, mask, bkv, bproj, wqt, wkvt, wpt,
                                             bqs, tbl, out, mode);
    }
}